// Round 10
// baseline (373.677 us; speedup 1.0000x reference)
//
#include <hip/hip_runtime.h>

// DCRNN cell: 3x diffusion conv (fwd/bwd, K=3 Chebyshev) + GRU gating.
// N=50000 nodes, E=800000 edges, F_IN=32, F_OUT=64, fan=96.
// Round 10: panel-major T matrices + ONE KERNEL LAUNCH PER PANEL (R9's
// blockIdx.z panels ran concurrently -> working set never fit L2; kernel
// boundaries are the only guaranteed serialization). Per dispatch: 3.2MB
// source panel < 4MB per-XCD L2.

#define NTHREADS 256
#define BKT_BITS 10
#define BKT_NODES 1024
#define STG_CAP 32768   // per-bucket staging capacity (expected ~16.4K)

typedef unsigned short u16;
typedef unsigned int u32;
typedef unsigned long long u64;
typedef __attribute__((ext_vector_type(8))) short short8;   // 8 bf16 (4 VGPRs)
typedef __attribute__((ext_vector_type(4))) float f32x4;

__device__ __forceinline__ float sigmoidf_(float x) { return 1.f / (1.f + __expf(-x)); }
__device__ __forceinline__ float b2f_lo(u32 u) { return __uint_as_float(u << 16); }
__device__ __forceinline__ float b2f_hi(u32 u) { return __uint_as_float(u & 0xffff0000u); }
__device__ __forceinline__ u16 f2b(float f) {
    u32 u = __float_as_uint(f);
    return (u16)((u + 0x7fffu + ((u >> 16) & 1u)) >> 16);
}
__device__ __forceinline__ u32 pack2(float a, float b) {
    return (u32)f2b(a) | ((u32)f2b(b) << 16);
}

// ---------------------------------------------------------------- edge decode

__device__ __forceinline__ void load_edge(const int* ei, int e, int E, int i64,
                                          int& r, int& c) {
    if (i64) {
        const long long* p = (const long long*)ei;
        r = (int)p[e]; c = (int)p[E + e];
    } else {
        r = ei[e]; c = ei[E + e];
    }
}

__global__ void detect_i64_kernel(const int* ei, int n_check, int* flag) {
    __shared__ int any;
    if (threadIdx.x == 0) any = 0;
    __syncthreads();
    int local = 0;
    for (int i = threadIdx.x; i < n_check; i += blockDim.x)
        if (ei[2 * i + 1] != 0) local = 1;
    if (local) any = 1;  // benign race
    __syncthreads();
    if (threadIdx.x == 0) *flag = (any ? 0 : 1);  // 1 => int64 layout
}

// ---- Pass 1: bin edges into node-range buckets (both directions). ----
__global__ __launch_bounds__(1024) void bin_kernel(
    const int* __restrict__ ei, const int* __restrict__ flag, const float* __restrict__ ew,
    int* gCntF, int* gCntB, uint2* __restrict__ stgF, uint2* __restrict__ stgB,
    int E, int NB) {
    __shared__ int cF[64], cB[64], bF[64], bB[64];
    int t = threadIdx.x;
    if (t < NB) { cF[t] = 0; cB[t] = 0; }
    __syncthreads();
    int i64 = *flag;
    int r[4], c[4], e[4]; float w[4];
#pragma unroll
    for (int k = 0; k < 4; ++k) {
        e[k] = blockIdx.x * 4096 + k * 1024 + t;
        if (e[k] < E) {
            load_edge(ei, e[k], E, i64, r[k], c[k]);
            w[k] = ew[e[k]];
            atomicAdd(&cF[c[k] >> BKT_BITS], 1);
            atomicAdd(&cB[r[k] >> BKT_BITS], 1);
        }
    }
    __syncthreads();
    if (t < NB) bF[t] = atomicAdd(&gCntF[t], cF[t]);
    if (t >= 256 && t < 256 + NB) bB[t - 256] = atomicAdd(&gCntB[t - 256], cB[t - 256]);
    __syncthreads();
    if (t < NB) cF[t] = 0;                      // reuse as intra-block cursor
    if (t >= 256 && t < 256 + NB) cB[t - 256] = 0;
    __syncthreads();
#pragma unroll
    for (int k = 0; k < 4; ++k) {
        if (e[k] < E) {
            int jf = c[k] >> BKT_BITS;
            int pf = bF[jf] + atomicAdd(&cF[jf], 1);
            stgF[(size_t)jf * STG_CAP + pf] =
                make_uint2(__float_as_uint(w[k]), ((u32)r[k] << BKT_BITS) | (u32)(c[k] & (BKT_NODES - 1)));
            int jb = r[k] >> BKT_BITS;
            int pb = bB[jb] + atomicAdd(&cB[jb], 1);
            stgB[(size_t)jb * STG_CAP + pb] =
                make_uint2(__float_as_uint(w[k]), ((u32)c[k] << BKT_BITS) | (u32)(r[k] & (BKT_NODES - 1)));
        }
    }
}

// ---- tiny scan over bucket totals -> CSR region bases ----
__global__ void bktscan_kernel(const int* __restrict__ gCntF, const int* __restrict__ gCntB,
                               int* bBaseF, int* bBaseB, int* of, int* ob,
                               int NB, int N, int E) {
    if (threadIdx.x == 0) {
        int s = 0;
        for (int j = 0; j < NB; ++j) { bBaseF[j] = s; s += gCntF[j]; }
        bBaseF[NB] = s; of[N] = E;
    }
    if (threadIdx.x == 1) {
        int s = 0;
        for (int j = 0; j < NB; ++j) { bBaseB[j] = s; s += gCntB[j]; }
        bBaseB[NB] = s; ob[N] = E;
    }
}

// ---- Pass 2a: weighted degrees per bucket, accumulated in LDS. ----
__global__ __launch_bounds__(1024) void bktdeg_kernel(
    const uint2* __restrict__ stgF, const uint2* __restrict__ stgB,
    const int* __restrict__ gCntF, const int* __restrict__ gCntB,
    float* __restrict__ deg_in, float* __restrict__ deg_out, int N, int NB) {
    __shared__ float acc[BKT_NODES];
    int j = blockIdx.x, t = threadIdx.x;
    bool fwd = j < NB;
    int jb = fwd ? j : j - NB;
    acc[t] = 0.f;
    __syncthreads();
    const uint2* stg = (fwd ? stgF : stgB) + (size_t)jb * STG_CAP;
    int m = fwd ? gCntF[jb] : gCntB[jb];
    for (int i = t; i < m; i += 1024) {
        uint2 p = stg[i];
        atomicAdd(&acc[p.y & (BKT_NODES - 1)], __uint_as_float(p.x));
    }
    __syncthreads();
    int n = jb * BKT_NODES + t;
    if (n < N) { if (fwd) deg_in[n] = acc[t]; else deg_out[n] = acc[t]; }
}

// ---- Pass 2b: per-node offs + exact CSR payload (packed u32). ----
__global__ __launch_bounds__(1024) void bktcsr_kernel(
    const uint2* __restrict__ stgF, const uint2* __restrict__ stgB,
    const int* __restrict__ gCntF, const int* __restrict__ gCntB,
    const int* __restrict__ bBaseF, const int* __restrict__ bBaseB,
    const float* __restrict__ deg_in, const float* __restrict__ deg_out,
    int* __restrict__ of, int* __restrict__ ob,
    u32* __restrict__ pf, u32* __restrict__ pb, int N, int NB) {
    __shared__ int cnt[BKT_NODES], scn[BKT_NODES];
    int j = blockIdx.x, t = threadIdx.x;
    bool fwd = j < NB;
    int jb = fwd ? j : j - NB;
    const uint2* stg = (fwd ? stgF : stgB) + (size_t)jb * STG_CAP;
    int m = fwd ? gCntF[jb] : gCntB[jb];
    int base = fwd ? bBaseF[jb] : bBaseB[jb];
    const float* degS = fwd ? deg_out : deg_in;  // coeff divides by SRC-side degree
    cnt[t] = 0;
    __syncthreads();
    for (int i = t; i < m; i += 1024) atomicAdd(&cnt[stg[i].y & (BKT_NODES - 1)], 1);
    __syncthreads();
    int v = cnt[t];
    scn[t] = v;
    __syncthreads();
    for (int d = 1; d < 1024; d <<= 1) {
        int x = (t >= d) ? scn[t - d] : 0;
        __syncthreads();
        scn[t] += x;
        __syncthreads();
    }
    int ex = scn[t] - v;
    int n = jb * BKT_NODES + t;
    if (n < N) { if (fwd) of[n] = base + ex; else ob[n] = base + ex; }
    cnt[t] = ex;  // reuse as cursor
    __syncthreads();
    for (int i = t; i < m; i += 1024) {
        uint2 p = stg[i];
        int dl = p.y & (BKT_NODES - 1);
        int src = p.y >> BKT_BITS;
        float coeff = __uint_as_float(p.x) / degS[src];
        int pos = base + atomicAdd(&cnt[dl], 1);
        u32 packed = ((u32)src << 16) | (u32)f2b(coeff);  // assumes src < 65536
        if (fwd) pf[pos] = packed; else pb[pos] = packed;
    }
}

// XH = [X | H] in bf16, PANEL-MAJOR [3][N][32]. Thread emits 8 bf16 (1 uint4).
__global__ void build_xh_kernel(const float4* __restrict__ X4, const float4* __restrict__ H4,
                                uint4* __restrict__ XH, int N) {
    int idx = blockIdx.x * blockDim.x + threadIdx.x;
    if (idx >= N * 12) return;
    int n = idx / 12, c = idx % 12;          // c: uint4 index within 96-col row
    float4 a, b;
    if (c < 4) { a = X4[n * 8 + c * 2]; b = X4[n * 8 + c * 2 + 1]; }
    else       { a = H4[n * 16 + (c - 4) * 2]; b = H4[n * 16 + (c - 4) * 2 + 1]; }
    uint4 o;
    o.x = pack2(a.x, a.y); o.y = pack2(a.z, a.w);
    o.z = pack2(b.x, b.y); o.w = pack2(b.z, b.w);
    int p = c >> 2, q = c & 3;               // panel, uint4-within-panel
    XH[(size_t)p * N * 4 + (size_t)n * 4 + q] = o;
}

#define GACC(vv, ww) \
    a0 += (ww) * b2f_lo((vv).x); a1 += (ww) * b2f_hi((vv).x); \
    a2 += (ww) * b2f_lo((vv).y); a3 += (ww) * b2f_hi((vv).y); \
    a4 += (ww) * b2f_lo((vv).z); a5 += (ww) * b2f_hi((vv).z); \
    a6 += (ww) * b2f_lo((vv).w); a7 += (ww) * b2f_hi((vv).w);

// Panelized dual-direction gather, ONE PANEL PER LAUNCH (panel = kernel arg).
// Source/dest panel-major [NP][N][32] bf16. grid = (ceil(N/96), 2 dirs).
// out[n] = sum_e w[e] * x[src[e]]   (CHEBY: 2*sum - base[n]).
template <int CHEBY>
__global__ __launch_bounds__(384) void gatherp_kernel(
    const uint4* __restrict__ xf, const uint4* __restrict__ xb,
    const int* __restrict__ offs_f, const u32* __restrict__ pf,
    const int* __restrict__ offs_b, const u32* __restrict__ pb,
    const uint4* __restrict__ base, uint4* __restrict__ outf, uint4* __restrict__ outb,
    int N, int panel) {
    const uint4* x; const int* offs; const u32* pr; uint4* out;
    if (blockIdx.y == 0) { x = xf; offs = offs_f; pr = pf; out = outf; }
    else                 { x = xb; offs = offs_b; pr = pb; out = outb; }
    size_t pbase = (size_t)panel * N * 4;   // panel offset (uint4 units)
    const uint4* xp = x + pbase;
    int n = blockIdx.x * 96 + threadIdx.y;
    if (n >= N) return;
    int c = threadIdx.x;  // 0..3 (16B lanes over the 64B panel row)
    int s0 = offs[n], s1 = offs[n + 1];
    float a0 = 0, a1 = 0, a2 = 0, a3 = 0, a4 = 0, a5 = 0, a6 = 0, a7 = 0;
    int o = s0;
    for (; o + 4 <= s1; o += 4) {
        u32 p0 = pr[o], p1 = pr[o + 1], p2 = pr[o + 2], p3 = pr[o + 3];
        uint4 v0 = xp[(size_t)(p0 >> 16) * 4 + c];
        uint4 v1 = xp[(size_t)(p1 >> 16) * 4 + c];
        uint4 v2 = xp[(size_t)(p2 >> 16) * 4 + c];
        uint4 v3 = xp[(size_t)(p3 >> 16) * 4 + c];
        float w0 = b2f_lo(p0), w1 = b2f_lo(p1), w2 = b2f_lo(p2), w3 = b2f_lo(p3);
        GACC(v0, w0) GACC(v1, w1) GACC(v2, w2) GACC(v3, w3)
    }
    for (; o < s1; ++o) {
        u32 p0 = pr[o];
        uint4 v0 = xp[(size_t)(p0 >> 16) * 4 + c];
        float w0 = b2f_lo(p0);
        GACC(v0, w0)
    }
    size_t oi = pbase + (size_t)n * 4 + c;
    if (CHEBY) {
        uint4 bv = base[oi];
        a0 = 2.f * a0 - b2f_lo(bv.x); a1 = 2.f * a1 - b2f_hi(bv.x);
        a2 = 2.f * a2 - b2f_lo(bv.y); a3 = 2.f * a3 - b2f_hi(bv.y);
        a4 = 2.f * a4 - b2f_lo(bv.z); a5 = 2.f * a5 - b2f_hi(bv.z);
        a6 = 2.f * a6 - b2f_lo(bv.w); a7 = 2.f * a7 - b2f_hi(bv.w);
    }
    uint4 ov;
    ov.x = pack2(a0, a1); ov.y = pack2(a2, a3);
    ov.z = pack2(a4, a5); ov.w = pack2(a6, a7);
    out[oi] = ov;
}

// Fuse + swizzle gate weights into MFMA-fragment-linear bf16.
__global__ void prep_weights_kernel(const float* __restrict__ Wz, const float* __restrict__ Wr,
                                    const float* __restrict__ Wh, u16* __restrict__ wf_all) {
    const int KS = 96 * 64;
    int g = blockIdx.x;
    const float* W = (g == 0) ? Wz : (g == 1) ? Wr : Wh;
    u16* wf = wf_all + (size_t)g * 30720;
    for (int i = threadIdx.x; i < 30720; i += blockDim.x) {
        int j = i & 7, lane = (i >> 3) & 63, ct = (i >> 9) & 3, kt = i >> 11;
        int k = kt * 32 + (lane >> 4) * 8 + j;
        int col = ct * 16 + (lane & 15);
        int m = k / 96, fr = k - m * 96;
        int off = (m == 0) ? 0 : (m == 1) ? KS : (m == 2) ? 4 * KS : (m == 3) ? 2 * KS : 5 * KS;
        float v = W[off + fr * 64 + col];
        if (m == 0) v += W[3 * KS + fr * 64 + col];
        wf[i] = f2b(v);
    }
}

// Fused Z+R GEMM. A matrices in 3-panel layout (panel stride N*32 u16).
// Writes Z (bf16, linear [N,64]) and HR = H*sigmoid (bf16, 2-panel layout).
__global__ __launch_bounds__(512) void gemm_zr_kernel(
    const u16* __restrict__ A0, const u16* __restrict__ A1, const u16* __restrict__ A2,
    const u16* __restrict__ A3, const u16* __restrict__ A4,
    const u16* __restrict__ wfZ, const u16* __restrict__ wfR,
    const float* __restrict__ bz, const float* __restrict__ br,
    const float* __restrict__ H,
    u16* __restrict__ ZB, u16* __restrict__ HR, int N) {
    __shared__ u16 wl[30720];  // 61440 B -> 2 blocks/CU
    int t = threadIdx.x;
    {
        const uint4* src = (const uint4*)wfZ;
        uint4* dst = (uint4*)wl;
        for (int i = t; i < 3840; i += 512) dst[i] = src[i];
    }

    int lane = t & 63, w = t >> 6;
    int rowBase = blockIdx.x * 128 + w * 16;
    int arow = rowBase + (lane & 15);
    int cf = (lane >> 4) * 8;
    int rsub = (lane >> 4) * 4;
    size_t ps = (size_t)N * 32;   // panel stride (u16)

    // Load all 15 A fragments (held across both phases).
    short8 afr[15];
    const u16* As[5] = {A0, A1, A2, A3, A4};
#pragma unroll
    for (int m = 0; m < 5; ++m) {
        const u16* a = As[m] + (size_t)arow * 32 + cf;
        afr[m * 3 + 0] = *(const short8*)(a);
        afr[m * 3 + 1] = *(const short8*)(a + ps);
        afr[m * 3 + 2] = *(const short8*)(a + 2 * ps);
    }
    __syncthreads();

    // ---- phase Z ----
    {
        f32x4 acc[4];
#pragma unroll
        for (int ct = 0; ct < 4; ++ct) {
            float b = bz[ct * 16 + (lane & 15)];
            acc[ct] = (f32x4){b, b, b, b};
        }
#pragma unroll
        for (int ktg = 0; ktg < 15; ++ktg)
#pragma unroll
            for (int ct = 0; ct < 4; ++ct) {
                short8 bfrag = *(const short8*)(&wl[((ktg * 4 + ct) * 64 + lane) * 8]);
                acc[ct] = __builtin_amdgcn_mfma_f32_16x16x32_bf16(afr[ktg], bfrag, acc[ct], 0, 0, 0);
            }
#pragma unroll
        for (int ct = 0; ct < 4; ++ct) {
            int col = ct * 16 + (lane & 15);
#pragma unroll
            for (int j = 0; j < 4; ++j) {
                int grow = rowBase + rsub + j;
                if (grow >= N) continue;
                ZB[(size_t)grow * 64 + col] = f2b(sigmoidf_(acc[ct][j]));
            }
        }
    }
    __syncthreads();  // all reads of wl (Z weights) done
    {
        const uint4* src = (const uint4*)wfR;
        uint4* dst = (uint4*)wl;
        for (int i = t; i < 3840; i += 512) dst[i] = src[i];
    }
    __syncthreads();

    // ---- phase R ----
    {
        f32x4 acc[4];
#pragma unroll
        for (int ct = 0; ct < 4; ++ct) {
            float b = br[ct * 16 + (lane & 15)];
            acc[ct] = (f32x4){b, b, b, b};
        }
#pragma unroll
        for (int ktg = 0; ktg < 15; ++ktg)
#pragma unroll
            for (int ct = 0; ct < 4; ++ct) {
                short8 bfrag = *(const short8*)(&wl[((ktg * 4 + ct) * 64 + lane) * 8]);
                acc[ct] = __builtin_amdgcn_mfma_f32_16x16x32_bf16(afr[ktg], bfrag, acc[ct], 0, 0, 0);
            }
#pragma unroll
        for (int ct = 0; ct < 4; ++ct) {
            int col = ct * 16 + (lane & 15);
#pragma unroll
            for (int j = 0; j < 4; ++j) {
                int grow = rowBase + rsub + j;
                if (grow >= N) continue;
                size_t bi = (size_t)grow * 64 + col;
                // HR in 2-panel layout
                HR[(size_t)(col >> 5) * ps + (size_t)grow * 32 + (col & 31)] =
                    f2b(H[bi] * sigmoidf_(acc[ct][j]));
            }
        }
    }
}

// H~ GEMM + GRU combine. X-part (k3=0) = panel 0 of ZR buffers; H-part
// (k3=1,2) = 2-panel HR-propagated buffers. Z read bf16 linear.
__global__ __launch_bounds__(512) void gemm_h_kernel(
    const u16* __restrict__ AX0, const u16* __restrict__ AX1, const u16* __restrict__ AX2,
    const u16* __restrict__ AX3, const u16* __restrict__ AX4,
    const u16* __restrict__ AH0, const u16* __restrict__ AH1, const u16* __restrict__ AH2,
    const u16* __restrict__ AH3, const u16* __restrict__ AH4,
    const u16* __restrict__ wfrag, const float* __restrict__ bias,
    const float* __restrict__ H, const u16* __restrict__ ZB,
    float* __restrict__ Out, int N) {
    __shared__ u16 wl[30720];
    int t = threadIdx.x;
    {
        const uint4* src = (const uint4*)wfrag;
        uint4* dst = (uint4*)wl;
        for (int i = t; i < 3840; i += 512) dst[i] = src[i];
    }
    __syncthreads();

    int lane = t & 63, w = t >> 6;
    int rowBase = blockIdx.x * 128 + w * 16;
    int arow = rowBase + (lane & 15);
    int cf = (lane >> 4) * 8;
    size_t ps = (size_t)N * 32;

    f32x4 acc[4];
#pragma unroll
    for (int ct = 0; ct < 4; ++ct) {
        float b = bias[ct * 16 + (lane & 15)];
        acc[ct] = (f32x4){b, b, b, b};
    }

    const u16* AXs[5] = {AX0, AX1, AX2, AX3, AX4};
    const u16* AHs[5] = {AH0, AH1, AH2, AH3, AH4};
#pragma unroll
    for (int m = 0; m < 5; ++m) {
        const u16* ax = AXs[m] + (size_t)arow * 32 + cf;   // panel 0
        const u16* ah = AHs[m] + (size_t)arow * 32 + cf;
#pragma unroll
        for (int k3 = 0; k3 < 3; ++k3) {
            short8 a = (k3 == 0) ? *(const short8*)ax
                                 : *(const short8*)(ah + (size_t)(k3 - 1) * ps);
            int ktg = m * 3 + k3;
#pragma unroll
            for (int ct = 0; ct < 4; ++ct) {
                short8 b = *(const short8*)(&wl[((ktg * 4 + ct) * 64 + lane) * 8]);
                acc[ct] = __builtin_amdgcn_mfma_f32_16x16x32_bf16(a, b, acc[ct], 0, 0, 0);
            }
        }
    }

    int rsub = (lane >> 4) * 4;
#pragma unroll
    for (int ct = 0; ct < 4; ++ct) {
        int col = ct * 16 + (lane & 15);
#pragma unroll
        for (int j = 0; j < 4; ++j) {
            int grow = rowBase + rsub + j;
            if (grow >= N) continue;
            size_t bi = (size_t)grow * 64 + col;
            float z = b2f_lo((u32)ZB[bi]);
            Out[bi] = z * H[bi] + (1.f - z) * tanhf(acc[ct][j]);
        }
    }
}

// ---------------------------------------------------------------- launch

extern "C" void kernel_launch(void* const* d_in, const int* in_sizes, int n_in,
                              void* d_out, int out_size, void* d_ws, size_t ws_size,
                              hipStream_t stream) {
    const float* X  = (const float*)d_in[0];
    const int*   ei = (const int*)d_in[1];
    const float* ew = (const float*)d_in[2];
    const float* H  = (const float*)d_in[3];
    const float* Wz = (const float*)d_in[4];
    const float* bz = (const float*)d_in[5];
    const float* Wr = (const float*)d_in[6];
    const float* br = (const float*)d_in[7];
    const float* Wh = (const float*)d_in[8];
    const float* bh = (const float*)d_in[9];
    float* out = (float*)d_out;

    const int N = in_sizes[0] / 32;   // 50000
    const int E = in_sizes[2];        // 800000
    const int NB = (N + BKT_NODES - 1) >> BKT_BITS;  // 49 (code assumes NB <= 64)

    // ---- workspace carve (256B aligned) ----
    char* wp = (char*)d_ws;
    auto alloc = [&](size_t nbytes) -> void* {
        void* p = (void*)wp;
        wp += (nbytes + 255) & ~(size_t)255;
        return p;
    };
    u16* XH   = (u16*)alloc((size_t)N * 96 * 2);   // 3-panel [3][N][32]
    u16* T1o  = (u16*)alloc((size_t)N * 96 * 2);
    u16* T1i  = (u16*)alloc((size_t)N * 96 * 2);
    u16* S2o  = (u16*)alloc((size_t)N * 96 * 2);
    u16* S2i  = (u16*)alloc((size_t)N * 96 * 2);
    u16* HR   = (u16*)alloc((size_t)N * 64 * 2);   // 2-panel [2][N][32]
    u16* T1oH = (u16*)alloc((size_t)N * 64 * 2);
    u16* T1iH = (u16*)alloc((size_t)N * 64 * 2);
    u16* S2oH = (u16*)alloc((size_t)N * 64 * 2);
    u16* S2iH = (u16*)alloc((size_t)N * 64 * 2);
    u16* ZB   = (u16*)alloc((size_t)N * 64 * 2);   // Z gate, bf16 linear
    float* deg_in  = (float*)alloc((size_t)N * 4);
    float* deg_out = (float*)alloc((size_t)N * 4);
    int* offs_f = (int*)alloc((size_t)(N + 1) * 4);
    int* offs_b = (int*)alloc((size_t)(N + 1) * 4);
    u32* pair_f = (u32*)alloc((size_t)E * 4);
    u32* pair_b = (u32*)alloc((size_t)E * 4);
    uint2* stgF = (uint2*)alloc((size_t)NB * STG_CAP * 8);
    uint2* stgB = (uint2*)alloc((size_t)NB * STG_CAP * 8);
    u16* wf_all = (u16*)alloc((size_t)3 * 30720 * 2);
    int* gCntF  = (int*)alloc(64 * 4);
    int* gCntB  = (int*)alloc(64 * 4);
    int* bBaseF = (int*)alloc(65 * 4);
    int* bBaseB = (int*)alloc(65 * 4);
    int* flag   = (int*)alloc(256);

    const int xhBlocks = (N * 12 + NTHREADS - 1) / NTHREADS;
    const int gemmBlocks = (N + 127) / 128;
    const int binBlocks = (E + 4095) / 4096;
    dim3 gpBlock(4, 96);
    dim3 gpGrid((N + 95) / 96, 2);   // one panel per launch

    // ---- edge preprocessing (bucketed CSR build) ----
    hipMemsetAsync(gCntF, 0, 64 * 4, stream);
    hipMemsetAsync(gCntB, 0, 64 * 4, stream);

    detect_i64_kernel<<<1, 256, 0, stream>>>(ei, E < 8192 ? E : 8192, flag);
    prep_weights_kernel<<<3, 256, 0, stream>>>(Wz, Wr, Wh, wf_all);
    bin_kernel<<<binBlocks, 1024, 0, stream>>>(ei, flag, ew, gCntF, gCntB, stgF, stgB, E, NB);
    bktscan_kernel<<<1, 64, 0, stream>>>(gCntF, gCntB, bBaseF, bBaseB, offs_f, offs_b, NB, N, E);
    bktdeg_kernel<<<2 * NB, 1024, 0, stream>>>(stgF, stgB, gCntF, gCntB, deg_in, deg_out, N, NB);
    bktcsr_kernel<<<2 * NB, 1024, 0, stream>>>(stgF, stgB, gCntF, gCntB, bBaseF, bBaseB,
                                               deg_in, deg_out, offs_f, offs_b,
                                               pair_f, pair_b, N, NB);

    // ---- phase ZR: shared T matrices on XH = [X|H] (per-panel launches) ----
    build_xh_kernel<<<xhBlocks, NTHREADS, 0, stream>>>((const float4*)X, (const float4*)H,
                                                       (uint4*)XH, N);
    for (int p = 0; p < 3; ++p)
        gatherp_kernel<0><<<gpGrid, gpBlock, 0, stream>>>(
            (const uint4*)XH, (const uint4*)XH, offs_f, pair_f, offs_b, pair_b,
            nullptr, (uint4*)T1o, (uint4*)T1i, N, p);
    for (int p = 0; p < 3; ++p)
        gatherp_kernel<1><<<gpGrid, gpBlock, 0, stream>>>(
            (const uint4*)T1o, (const uint4*)T1i, offs_f, pair_f, offs_b, pair_b,
            (const uint4*)XH, (uint4*)S2o, (uint4*)S2i, N, p);

    // Fused Z+R gates (A read once): Z -> ZB (bf16), HR = H*sigmoid (2-panel)
    gemm_zr_kernel<<<gemmBlocks, 512, 0, stream>>>(
        XH, T1o, T1i, S2o, S2i, wf_all, wf_all + 30720, bz, br, H, ZB, HR, N);

    // ---- phase H: propagate the 64-col H*R part (per-panel launches) ----
    for (int p = 0; p < 2; ++p)
        gatherp_kernel<0><<<gpGrid, gpBlock, 0, stream>>>(
            (const uint4*)HR, (const uint4*)HR, offs_f, pair_f, offs_b, pair_b,
            nullptr, (uint4*)T1oH, (uint4*)T1iH, N, p);
    for (int p = 0; p < 2; ++p)
        gatherp_kernel<1><<<gpGrid, gpBlock, 0, stream>>>(
            (const uint4*)T1oH, (const uint4*)T1iH, offs_f, pair_f, offs_b, pair_b,
            (const uint4*)HR, (uint4*)S2oH, (uint4*)S2iH, N, p);

    // H~ gate + GRU combine; A = [panel0 of ZR buffers | 2-panel H-part]
    gemm_h_kernel<<<gemmBlocks, 512, 0, stream>>>(
        XH, T1o, T1i, S2o, S2i, HR, T1oH, T1iH, S2oH, S2iH,
        wf_all + 2 * 30720, bh, H, ZB, out, N);
}

// Round 11
// 290.948 us; speedup vs baseline: 1.2843x; 1.2843x over previous
//
#include <hip/hip_runtime.h>

// DCRNN cell: 3x diffusion conv (fwd/bwd, K=3 Chebyshev) + GRU gating.
// N=50000 nodes, E=800000 edges, F_IN=32, F_OUT=64, fan=96.
// Round 11: REVERT to R8 structure (linear layouts; panelization R9/R10
// regressed). Fix: prep_weights was 3 blocks / 46us serial latency-bound
// since R3 -> one-thread-per-element, 360 blocks (~3us).

#define NTHREADS 256
#define BKT_BITS 10
#define BKT_NODES 1024
#define STG_CAP 32768   // per-bucket staging capacity (expected ~16.4K)

typedef unsigned short u16;
typedef unsigned int u32;
typedef unsigned long long u64;
typedef __attribute__((ext_vector_type(8))) short short8;   // 8 bf16 (4 VGPRs)
typedef __attribute__((ext_vector_type(4))) float f32x4;

__device__ __forceinline__ float sigmoidf_(float x) { return 1.f / (1.f + __expf(-x)); }
__device__ __forceinline__ float b2f_lo(u32 u) { return __uint_as_float(u << 16); }
__device__ __forceinline__ float b2f_hi(u32 u) { return __uint_as_float(u & 0xffff0000u); }
__device__ __forceinline__ u16 f2b(float f) {
    u32 u = __float_as_uint(f);
    return (u16)((u + 0x7fffu + ((u >> 16) & 1u)) >> 16);
}
__device__ __forceinline__ u32 pack2(float a, float b) {
    return (u32)f2b(a) | ((u32)f2b(b) << 16);
}

// ---------------------------------------------------------------- edge decode

__device__ __forceinline__ void load_edge(const int* ei, int e, int E, int i64,
                                          int& r, int& c) {
    if (i64) {
        const long long* p = (const long long*)ei;
        r = (int)p[e]; c = (int)p[E + e];
    } else {
        r = ei[e]; c = ei[E + e];
    }
}

__global__ void detect_i64_kernel(const int* ei, int n_check, int* flag) {
    __shared__ int any;
    if (threadIdx.x == 0) any = 0;
    __syncthreads();
    int local = 0;
    for (int i = threadIdx.x; i < n_check; i += blockDim.x)
        if (ei[2 * i + 1] != 0) local = 1;
    if (local) any = 1;  // benign race
    __syncthreads();
    if (threadIdx.x == 0) *flag = (any ? 0 : 1);  // 1 => int64 layout
}

// ---- Pass 1: bin edges into node-range buckets (both directions). ----
__global__ __launch_bounds__(1024) void bin_kernel(
    const int* __restrict__ ei, const int* __restrict__ flag, const float* __restrict__ ew,
    int* gCntF, int* gCntB, uint2* __restrict__ stgF, uint2* __restrict__ stgB,
    int E, int NB) {
    __shared__ int cF[64], cB[64], bF[64], bB[64];
    int t = threadIdx.x;
    if (t < NB) { cF[t] = 0; cB[t] = 0; }
    __syncthreads();
    int i64 = *flag;
    int r[4], c[4], e[4]; float w[4];
#pragma unroll
    for (int k = 0; k < 4; ++k) {
        e[k] = blockIdx.x * 4096 + k * 1024 + t;
        if (e[k] < E) {
            load_edge(ei, e[k], E, i64, r[k], c[k]);
            w[k] = ew[e[k]];
            atomicAdd(&cF[c[k] >> BKT_BITS], 1);
            atomicAdd(&cB[r[k] >> BKT_BITS], 1);
        }
    }
    __syncthreads();
    if (t < NB) bF[t] = atomicAdd(&gCntF[t], cF[t]);
    if (t >= 256 && t < 256 + NB) bB[t - 256] = atomicAdd(&gCntB[t - 256], cB[t - 256]);
    __syncthreads();
    if (t < NB) cF[t] = 0;                      // reuse as intra-block cursor
    if (t >= 256 && t < 256 + NB) cB[t - 256] = 0;
    __syncthreads();
#pragma unroll
    for (int k = 0; k < 4; ++k) {
        if (e[k] < E) {
            int jf = c[k] >> BKT_BITS;
            int pf = bF[jf] + atomicAdd(&cF[jf], 1);
            stgF[(size_t)jf * STG_CAP + pf] =
                make_uint2(__float_as_uint(w[k]), ((u32)r[k] << BKT_BITS) | (u32)(c[k] & (BKT_NODES - 1)));
            int jb = r[k] >> BKT_BITS;
            int pb = bB[jb] + atomicAdd(&cB[jb], 1);
            stgB[(size_t)jb * STG_CAP + pb] =
                make_uint2(__float_as_uint(w[k]), ((u32)c[k] << BKT_BITS) | (u32)(r[k] & (BKT_NODES - 1)));
        }
    }
}

// ---- tiny scan over bucket totals -> CSR region bases ----
__global__ void bktscan_kernel(const int* __restrict__ gCntF, const int* __restrict__ gCntB,
                               int* bBaseF, int* bBaseB, int* of, int* ob,
                               int NB, int N, int E) {
    if (threadIdx.x == 0) {
        int s = 0;
        for (int j = 0; j < NB; ++j) { bBaseF[j] = s; s += gCntF[j]; }
        bBaseF[NB] = s; of[N] = E;
    }
    if (threadIdx.x == 1) {
        int s = 0;
        for (int j = 0; j < NB; ++j) { bBaseB[j] = s; s += gCntB[j]; }
        bBaseB[NB] = s; ob[N] = E;
    }
}

// ---- Pass 2a: weighted degrees per bucket, accumulated in LDS. ----
__global__ __launch_bounds__(1024) void bktdeg_kernel(
    const uint2* __restrict__ stgF, const uint2* __restrict__ stgB,
    const int* __restrict__ gCntF, const int* __restrict__ gCntB,
    float* __restrict__ deg_in, float* __restrict__ deg_out, int N, int NB) {
    __shared__ float acc[BKT_NODES];
    int j = blockIdx.x, t = threadIdx.x;
    bool fwd = j < NB;
    int jb = fwd ? j : j - NB;
    acc[t] = 0.f;
    __syncthreads();
    const uint2* stg = (fwd ? stgF : stgB) + (size_t)jb * STG_CAP;
    int m = fwd ? gCntF[jb] : gCntB[jb];
    for (int i = t; i < m; i += 1024) {
        uint2 p = stg[i];
        atomicAdd(&acc[p.y & (BKT_NODES - 1)], __uint_as_float(p.x));
    }
    __syncthreads();
    int n = jb * BKT_NODES + t;
    if (n < N) { if (fwd) deg_in[n] = acc[t]; else deg_out[n] = acc[t]; }
}

// ---- Pass 2b: per-node offs + exact CSR payload (packed u32). ----
__global__ __launch_bounds__(1024) void bktcsr_kernel(
    const uint2* __restrict__ stgF, const uint2* __restrict__ stgB,
    const int* __restrict__ gCntF, const int* __restrict__ gCntB,
    const int* __restrict__ bBaseF, const int* __restrict__ bBaseB,
    const float* __restrict__ deg_in, const float* __restrict__ deg_out,
    int* __restrict__ of, int* __restrict__ ob,
    u32* __restrict__ pf, u32* __restrict__ pb, int N, int NB) {
    __shared__ int cnt[BKT_NODES], scn[BKT_NODES];
    int j = blockIdx.x, t = threadIdx.x;
    bool fwd = j < NB;
    int jb = fwd ? j : j - NB;
    const uint2* stg = (fwd ? stgF : stgB) + (size_t)jb * STG_CAP;
    int m = fwd ? gCntF[jb] : gCntB[jb];
    int base = fwd ? bBaseF[jb] : bBaseB[jb];
    const float* degS = fwd ? deg_out : deg_in;  // coeff divides by SRC-side degree
    cnt[t] = 0;
    __syncthreads();
    for (int i = t; i < m; i += 1024) atomicAdd(&cnt[stg[i].y & (BKT_NODES - 1)], 1);
    __syncthreads();
    int v = cnt[t];
    scn[t] = v;
    __syncthreads();
    for (int d = 1; d < 1024; d <<= 1) {
        int x = (t >= d) ? scn[t - d] : 0;
        __syncthreads();
        scn[t] += x;
        __syncthreads();
    }
    int ex = scn[t] - v;
    int n = jb * BKT_NODES + t;
    if (n < N) { if (fwd) of[n] = base + ex; else ob[n] = base + ex; }
    cnt[t] = ex;  // reuse as cursor
    __syncthreads();
    for (int i = t; i < m; i += 1024) {
        uint2 p = stg[i];
        int dl = p.y & (BKT_NODES - 1);
        int src = p.y >> BKT_BITS;
        float coeff = __uint_as_float(p.x) / degS[src];
        int pos = base + atomicAdd(&cnt[dl], 1);
        u32 packed = ((u32)src << 16) | (u32)f2b(coeff);  // assumes src < 65536
        if (fwd) pf[pos] = packed; else pb[pos] = packed;
    }
}

// XH = [X | H] in bf16. Each thread emits 8 bf16 (16B). N*12 chunks.
__global__ void build_xh_kernel(const float4* __restrict__ X4, const float4* __restrict__ H4,
                                uint4* __restrict__ XH, int N) {
    int idx = blockIdx.x * blockDim.x + threadIdx.x;
    if (idx >= N * 12) return;
    int n = idx / 12, c = idx % 12;
    float4 a, b;
    if (c < 4) { a = X4[n * 8 + c * 2]; b = X4[n * 8 + c * 2 + 1]; }
    else       { a = H4[n * 16 + (c - 4) * 2]; b = H4[n * 16 + (c - 4) * 2 + 1]; }
    uint4 o;
    o.x = pack2(a.x, a.y); o.y = pack2(a.z, a.w);
    o.z = pack2(b.x, b.y); o.w = pack2(b.z, b.w);
    XH[idx] = o;
}

#define GACC(vv, ww) \
    a0 += (ww) * b2f_lo((vv).x); a1 += (ww) * b2f_hi((vv).x); \
    a2 += (ww) * b2f_lo((vv).y); a3 += (ww) * b2f_hi((vv).y); \
    a4 += (ww) * b2f_lo((vv).z); a5 += (ww) * b2f_hi((vv).z); \
    a6 += (ww) * b2f_lo((vv).w); a7 += (ww) * b2f_hi((vv).w);

// Dual-direction bf16 gather, 96-col rows. blockDim = (12, 32). Unroll x4.
// out[n] = sum_e w[e] * x[src[e]]   (CHEBY: 2*sum - base[n]).
template <int CHEBY>
__global__ __launch_bounds__(384) void gather2_kernel(
    const uint4* __restrict__ xf, const uint4* __restrict__ xb,
    const int* __restrict__ offs_f, const u32* __restrict__ pf,
    const int* __restrict__ offs_b, const u32* __restrict__ pb,
    const uint4* __restrict__ base, uint4* __restrict__ outf, uint4* __restrict__ outb,
    int N) {
    const uint4* x; const int* offs; const u32* pr; uint4* out;
    if (blockIdx.y == 0) { x = xf; offs = offs_f; pr = pf; out = outf; }
    else                 { x = xb; offs = offs_b; pr = pb; out = outb; }
    int n = blockIdx.x * 32 + threadIdx.y;
    if (n >= N) return;
    int c = threadIdx.x;  // 0..11
    int s0 = offs[n], s1 = offs[n + 1];
    float a0 = 0, a1 = 0, a2 = 0, a3 = 0, a4 = 0, a5 = 0, a6 = 0, a7 = 0;
    int o = s0;
    for (; o + 4 <= s1; o += 4) {
        u32 p0 = pr[o], p1 = pr[o + 1], p2 = pr[o + 2], p3 = pr[o + 3];
        uint4 v0 = x[(size_t)(p0 >> 16) * 12 + c];
        uint4 v1 = x[(size_t)(p1 >> 16) * 12 + c];
        uint4 v2 = x[(size_t)(p2 >> 16) * 12 + c];
        uint4 v3 = x[(size_t)(p3 >> 16) * 12 + c];
        float w0 = b2f_lo(p0), w1 = b2f_lo(p1), w2 = b2f_lo(p2), w3 = b2f_lo(p3);
        GACC(v0, w0) GACC(v1, w1) GACC(v2, w2) GACC(v3, w3)
    }
    for (; o < s1; ++o) {
        u32 p0 = pr[o];
        uint4 v0 = x[(size_t)(p0 >> 16) * 12 + c];
        float w0 = b2f_lo(p0);
        GACC(v0, w0)
    }
    size_t oi = (size_t)n * 12 + c;
    if (CHEBY) {
        uint4 bv = base[oi];
        a0 = 2.f * a0 - b2f_lo(bv.x); a1 = 2.f * a1 - b2f_hi(bv.x);
        a2 = 2.f * a2 - b2f_lo(bv.y); a3 = 2.f * a3 - b2f_hi(bv.y);
        a4 = 2.f * a4 - b2f_lo(bv.z); a5 = 2.f * a5 - b2f_hi(bv.z);
        a6 = 2.f * a6 - b2f_lo(bv.w); a7 = 2.f * a7 - b2f_hi(bv.w);
    }
    uint4 ov;
    ov.x = pack2(a0, a1); ov.y = pack2(a2, a3);
    ov.z = pack2(a4, a5); ov.w = pack2(a6, a7);
    out[oi] = ov;
}

// Dual-direction bf16 gather, 64-col rows (phase-H H-part). blockDim = (8, 48).
template <int CHEBY>
__global__ __launch_bounds__(384) void gather2h_kernel(
    const uint4* __restrict__ xf, const uint4* __restrict__ xb,
    const int* __restrict__ offs_f, const u32* __restrict__ pf,
    const int* __restrict__ offs_b, const u32* __restrict__ pb,
    const uint4* __restrict__ base, uint4* __restrict__ outf, uint4* __restrict__ outb,
    int N) {
    const uint4* x; const int* offs; const u32* pr; uint4* out;
    if (blockIdx.y == 0) { x = xf; offs = offs_f; pr = pf; out = outf; }
    else                 { x = xb; offs = offs_b; pr = pb; out = outb; }
    int n = blockIdx.x * 48 + threadIdx.y;
    if (n >= N) return;
    int c = threadIdx.x;  // 0..7
    int s0 = offs[n], s1 = offs[n + 1];
    float a0 = 0, a1 = 0, a2 = 0, a3 = 0, a4 = 0, a5 = 0, a6 = 0, a7 = 0;
    int o = s0;
    for (; o + 4 <= s1; o += 4) {
        u32 p0 = pr[o], p1 = pr[o + 1], p2 = pr[o + 2], p3 = pr[o + 3];
        uint4 v0 = x[(size_t)(p0 >> 16) * 8 + c];
        uint4 v1 = x[(size_t)(p1 >> 16) * 8 + c];
        uint4 v2 = x[(size_t)(p2 >> 16) * 8 + c];
        uint4 v3 = x[(size_t)(p3 >> 16) * 8 + c];
        float w0 = b2f_lo(p0), w1 = b2f_lo(p1), w2 = b2f_lo(p2), w3 = b2f_lo(p3);
        GACC(v0, w0) GACC(v1, w1) GACC(v2, w2) GACC(v3, w3)
    }
    for (; o < s1; ++o) {
        u32 p0 = pr[o];
        uint4 v0 = x[(size_t)(p0 >> 16) * 8 + c];
        float w0 = b2f_lo(p0);
        GACC(v0, w0)
    }
    size_t oi = (size_t)n * 8 + c;
    if (CHEBY) {
        uint4 bv = base[oi];
        a0 = 2.f * a0 - b2f_lo(bv.x); a1 = 2.f * a1 - b2f_hi(bv.x);
        a2 = 2.f * a2 - b2f_lo(bv.y); a3 = 2.f * a3 - b2f_hi(bv.y);
        a4 = 2.f * a4 - b2f_lo(bv.z); a5 = 2.f * a5 - b2f_hi(bv.z);
        a6 = 2.f * a6 - b2f_lo(bv.w); a7 = 2.f * a7 - b2f_hi(bv.w);
    }
    uint4 ov;
    ov.x = pack2(a0, a1); ov.y = pack2(a2, a3);
    ov.z = pack2(a4, a5); ov.w = pack2(a6, a7);
    out[oi] = ov;
}

// Fuse + swizzle gate weights into MFMA-fragment-linear bf16.
// One thread per output element: 3*30720 = 92160 threads (was 3 blocks/46us).
__global__ void prep_weights_kernel(const float* __restrict__ Wz, const float* __restrict__ Wr,
                                    const float* __restrict__ Wh, u16* __restrict__ wf_all) {
    const int KS = 96 * 64;
    int idx = blockIdx.x * blockDim.x + threadIdx.x;
    if (idx >= 3 * 30720) return;
    int g = idx / 30720, i = idx - g * 30720;
    const float* W = (g == 0) ? Wz : (g == 1) ? Wr : Wh;
    int j = i & 7, lane = (i >> 3) & 63, ct = (i >> 9) & 3, kt = i >> 11;
    int k = kt * 32 + (lane >> 4) * 8 + j;
    int col = ct * 16 + (lane & 15);
    int m = k / 96, fr = k - m * 96;
    int off = (m == 0) ? 0 : (m == 1) ? KS : (m == 2) ? 4 * KS : (m == 3) ? 2 * KS : 5 * KS;
    float v = W[off + fr * 64 + col];
    if (m == 0) v += W[3 * KS + fr * 64 + col];
    wf_all[idx] = f2b(v);
}

// Fused Z+R GEMM: A (5 matrices, [N,96]) read ONCE into registers; two-phase
// LDS weight staging. Writes Z (bf16) and HR = H*sigmoid(accR) (bf16).
__global__ __launch_bounds__(512) void gemm_zr_kernel(
    const u16* __restrict__ A0, const u16* __restrict__ A1, const u16* __restrict__ A2,
    const u16* __restrict__ A3, const u16* __restrict__ A4,
    const u16* __restrict__ wfZ, const u16* __restrict__ wfR,
    const float* __restrict__ bz, const float* __restrict__ br,
    const float* __restrict__ H,
    u16* __restrict__ ZB, u16* __restrict__ HR, int N) {
    __shared__ u16 wl[30720];  // 61440 B -> 2 blocks/CU
    int t = threadIdx.x;
    {
        const uint4* src = (const uint4*)wfZ;
        uint4* dst = (uint4*)wl;
        for (int i = t; i < 3840; i += 512) dst[i] = src[i];
    }

    int lane = t & 63, w = t >> 6;
    int rowBase = blockIdx.x * 128 + w * 16;
    int arow = rowBase + (lane & 15);
    int cf = (lane >> 4) * 8;
    int rsub = (lane >> 4) * 4;

    // Load all 15 A fragments (held across both phases).
    short8 afr[15];
    const u16* As[5] = {A0, A1, A2, A3, A4};
#pragma unroll
    for (int m = 0; m < 5; ++m) {
        const u16* a = As[m] + (size_t)arow * 96 + cf;
        afr[m * 3 + 0] = *(const short8*)(a);
        afr[m * 3 + 1] = *(const short8*)(a + 32);
        afr[m * 3 + 2] = *(const short8*)(a + 64);
    }
    __syncthreads();

    // ---- phase Z ----
    {
        f32x4 acc[4];
#pragma unroll
        for (int ct = 0; ct < 4; ++ct) {
            float b = bz[ct * 16 + (lane & 15)];
            acc[ct] = (f32x4){b, b, b, b};
        }
#pragma unroll
        for (int ktg = 0; ktg < 15; ++ktg)
#pragma unroll
            for (int ct = 0; ct < 4; ++ct) {
                short8 bfrag = *(const short8*)(&wl[((ktg * 4 + ct) * 64 + lane) * 8]);
                acc[ct] = __builtin_amdgcn_mfma_f32_16x16x32_bf16(afr[ktg], bfrag, acc[ct], 0, 0, 0);
            }
#pragma unroll
        for (int ct = 0; ct < 4; ++ct) {
            int col = ct * 16 + (lane & 15);
#pragma unroll
            for (int j = 0; j < 4; ++j) {
                int grow = rowBase + rsub + j;
                if (grow >= N) continue;
                ZB[(size_t)grow * 64 + col] = f2b(sigmoidf_(acc[ct][j]));
            }
        }
    }
    __syncthreads();  // all reads of wl (Z weights) done
    {
        const uint4* src = (const uint4*)wfR;
        uint4* dst = (uint4*)wl;
        for (int i = t; i < 3840; i += 512) dst[i] = src[i];
    }
    __syncthreads();

    // ---- phase R ----
    {
        f32x4 acc[4];
#pragma unroll
        for (int ct = 0; ct < 4; ++ct) {
            float b = br[ct * 16 + (lane & 15)];
            acc[ct] = (f32x4){b, b, b, b};
        }
#pragma unroll
        for (int ktg = 0; ktg < 15; ++ktg)
#pragma unroll
            for (int ct = 0; ct < 4; ++ct) {
                short8 bfrag = *(const short8*)(&wl[((ktg * 4 + ct) * 64 + lane) * 8]);
                acc[ct] = __builtin_amdgcn_mfma_f32_16x16x32_bf16(afr[ktg], bfrag, acc[ct], 0, 0, 0);
            }
#pragma unroll
        for (int ct = 0; ct < 4; ++ct) {
            int col = ct * 16 + (lane & 15);
#pragma unroll
            for (int j = 0; j < 4; ++j) {
                int grow = rowBase + rsub + j;
                if (grow >= N) continue;
                size_t bi = (size_t)grow * 64 + col;
                HR[bi] = f2b(H[bi] * sigmoidf_(acc[ct][j]));
            }
        }
    }
}

// H~ GEMM + GRU combine: A split (X-part stride 96 from ZR buffers, H-part
// stride 64). out = Z*H + (1-Z)*tanh(acc), Z read as bf16.
__global__ __launch_bounds__(512) void gemm_h_kernel(
    const u16* __restrict__ AX0, const u16* __restrict__ AX1, const u16* __restrict__ AX2,
    const u16* __restrict__ AX3, const u16* __restrict__ AX4,
    const u16* __restrict__ AH0, const u16* __restrict__ AH1, const u16* __restrict__ AH2,
    const u16* __restrict__ AH3, const u16* __restrict__ AH4,
    const u16* __restrict__ wfrag, const float* __restrict__ bias,
    const float* __restrict__ H, const u16* __restrict__ ZB,
    float* __restrict__ Out, int N) {
    __shared__ u16 wl[30720];
    int t = threadIdx.x;
    {
        const uint4* src = (const uint4*)wfrag;
        uint4* dst = (uint4*)wl;
        for (int i = t; i < 3840; i += 512) dst[i] = src[i];
    }
    __syncthreads();

    int lane = t & 63, w = t >> 6;
    int rowBase = blockIdx.x * 128 + w * 16;
    int arow = rowBase + (lane & 15);
    int cf = (lane >> 4) * 8;

    f32x4 acc[4];
#pragma unroll
    for (int ct = 0; ct < 4; ++ct) {
        float b = bias[ct * 16 + (lane & 15)];
        acc[ct] = (f32x4){b, b, b, b};
    }

    const u16* AXs[5] = {AX0, AX1, AX2, AX3, AX4};
    const u16* AHs[5] = {AH0, AH1, AH2, AH3, AH4};
#pragma unroll
    for (int m = 0; m < 5; ++m) {
        const u16* ax = AXs[m] + (size_t)arow * 96 + cf;
        const u16* ah = AHs[m] + (size_t)arow * 64 + cf;
#pragma unroll
        for (int k3 = 0; k3 < 3; ++k3) {
            short8 a = (k3 == 0) ? *(const short8*)ax
                                 : *(const short8*)(ah + (k3 - 1) * 32);
            int ktg = m * 3 + k3;
#pragma unroll
            for (int ct = 0; ct < 4; ++ct) {
                short8 b = *(const short8*)(&wl[((ktg * 4 + ct) * 64 + lane) * 8]);
                acc[ct] = __builtin_amdgcn_mfma_f32_16x16x32_bf16(a, b, acc[ct], 0, 0, 0);
            }
        }
    }

    int rsub = (lane >> 4) * 4;
#pragma unroll
    for (int ct = 0; ct < 4; ++ct) {
        int col = ct * 16 + (lane & 15);
#pragma unroll
        for (int j = 0; j < 4; ++j) {
            int grow = rowBase + rsub + j;
            if (grow >= N) continue;
            size_t bi = (size_t)grow * 64 + col;
            float z = b2f_lo((u32)ZB[bi]);
            Out[bi] = z * H[bi] + (1.f - z) * tanhf(acc[ct][j]);
        }
    }
}

// ---------------------------------------------------------------- launch

extern "C" void kernel_launch(void* const* d_in, const int* in_sizes, int n_in,
                              void* d_out, int out_size, void* d_ws, size_t ws_size,
                              hipStream_t stream) {
    const float* X  = (const float*)d_in[0];
    const int*   ei = (const int*)d_in[1];
    const float* ew = (const float*)d_in[2];
    const float* H  = (const float*)d_in[3];
    const float* Wz = (const float*)d_in[4];
    const float* bz = (const float*)d_in[5];
    const float* Wr = (const float*)d_in[6];
    const float* br = (const float*)d_in[7];
    const float* Wh = (const float*)d_in[8];
    const float* bh = (const float*)d_in[9];
    float* out = (float*)d_out;

    const int N = in_sizes[0] / 32;   // 50000
    const int E = in_sizes[2];        // 800000
    const int NB = (N + BKT_NODES - 1) >> BKT_BITS;  // 49 (code assumes NB <= 64)

    // ---- workspace carve (256B aligned) ----
    char* wp = (char*)d_ws;
    auto alloc = [&](size_t nbytes) -> void* {
        void* p = (void*)wp;
        wp += (nbytes + 255) & ~(size_t)255;
        return p;
    };
    u16* XH   = (u16*)alloc((size_t)N * 96 * 2);   // [X|H], stays intact
    u16* T1o  = (u16*)alloc((size_t)N * 96 * 2);
    u16* T1i  = (u16*)alloc((size_t)N * 96 * 2);
    u16* S2o  = (u16*)alloc((size_t)N * 96 * 2);
    u16* S2i  = (u16*)alloc((size_t)N * 96 * 2);
    u16* HR   = (u16*)alloc((size_t)N * 64 * 2);   // H*R (phase-H H-part)
    u16* T1oH = (u16*)alloc((size_t)N * 64 * 2);
    u16* T1iH = (u16*)alloc((size_t)N * 64 * 2);
    u16* S2oH = (u16*)alloc((size_t)N * 64 * 2);
    u16* S2iH = (u16*)alloc((size_t)N * 64 * 2);
    u16* ZB   = (u16*)alloc((size_t)N * 64 * 2);   // Z gate, bf16
    float* deg_in  = (float*)alloc((size_t)N * 4);
    float* deg_out = (float*)alloc((size_t)N * 4);
    int* offs_f = (int*)alloc((size_t)(N + 1) * 4);
    int* offs_b = (int*)alloc((size_t)(N + 1) * 4);
    u32* pair_f = (u32*)alloc((size_t)E * 4);
    u32* pair_b = (u32*)alloc((size_t)E * 4);
    uint2* stgF = (uint2*)alloc((size_t)NB * STG_CAP * 8);
    uint2* stgB = (uint2*)alloc((size_t)NB * STG_CAP * 8);
    u16* wf_all = (u16*)alloc((size_t)3 * 30720 * 2);
    int* gCntF  = (int*)alloc(64 * 4);
    int* gCntB  = (int*)alloc(64 * 4);
    int* bBaseF = (int*)alloc(65 * 4);
    int* bBaseB = (int*)alloc(65 * 4);
    int* flag   = (int*)alloc(256);

    const int xhBlocks = (N * 12 + NTHREADS - 1) / NTHREADS;
    const int gemmBlocks = (N + 127) / 128;
    const int binBlocks = (E + 4095) / 4096;
    const int pwBlocks = (3 * 30720 + NTHREADS - 1) / NTHREADS;
    dim3 gatherBlock(12, 32);
    dim3 gatherGrid((N + 31) / 32, 2);
    dim3 gatherHBlock(8, 48);
    dim3 gatherHGrid((N + 47) / 48, 2);

    // ---- edge preprocessing (bucketed CSR build) ----
    hipMemsetAsync(gCntF, 0, 64 * 4, stream);
    hipMemsetAsync(gCntB, 0, 64 * 4, stream);

    detect_i64_kernel<<<1, 256, 0, stream>>>(ei, E < 8192 ? E : 8192, flag);
    prep_weights_kernel<<<pwBlocks, NTHREADS, 0, stream>>>(Wz, Wr, Wh, wf_all);
    bin_kernel<<<binBlocks, 1024, 0, stream>>>(ei, flag, ew, gCntF, gCntB, stgF, stgB, E, NB);
    bktscan_kernel<<<1, 64, 0, stream>>>(gCntF, gCntB, bBaseF, bBaseB, offs_f, offs_b, NB, N, E);
    bktdeg_kernel<<<2 * NB, 1024, 0, stream>>>(stgF, stgB, gCntF, gCntB, deg_in, deg_out, N, NB);
    bktcsr_kernel<<<2 * NB, 1024, 0, stream>>>(stgF, stgB, gCntF, gCntB, bBaseF, bBaseB,
                                               deg_in, deg_out, offs_f, offs_b,
                                               pair_f, pair_b, N, NB);

    // ---- phase ZR: shared T matrices on XH = [X|H] (96-col gathers) ----
    build_xh_kernel<<<xhBlocks, NTHREADS, 0, stream>>>((const float4*)X, (const float4*)H,
                                                       (uint4*)XH, N);
    gather2_kernel<0><<<gatherGrid, gatherBlock, 0, stream>>>(
        (const uint4*)XH, (const uint4*)XH, offs_f, pair_f, offs_b, pair_b,
        nullptr, (uint4*)T1o, (uint4*)T1i, N);
    gather2_kernel<1><<<gatherGrid, gatherBlock, 0, stream>>>(
        (const uint4*)T1o, (const uint4*)T1i, offs_f, pair_f, offs_b, pair_b,
        (const uint4*)XH, (uint4*)S2o, (uint4*)S2i, N);

    // Fused Z+R gates (A read once): Z -> ZB (bf16), HR = H*sigmoid (bf16)
    gemm_zr_kernel<<<gemmBlocks, 512, 0, stream>>>(
        XH, T1o, T1i, S2o, S2i, wf_all, wf_all + 30720, bz, br, H, ZB, HR, N);

    // ---- phase H: propagate only the 64-col H*R part (X-part reused from ZR) ----
    gather2h_kernel<0><<<gatherHGrid, gatherHBlock, 0, stream>>>(
        (const uint4*)HR, (const uint4*)HR, offs_f, pair_f, offs_b, pair_b,
        nullptr, (uint4*)T1oH, (uint4*)T1iH, N);
    gather2h_kernel<1><<<gatherHGrid, gatherHBlock, 0, stream>>>(
        (const uint4*)T1oH, (const uint4*)T1iH, offs_f, pair_f, offs_b, pair_b,
        (const uint4*)HR, (uint4*)S2oH, (uint4*)S2iH, N);

    // H~ gate + GRU combine fused; A = [X-part from ZR buffers | H-part 64-col]
    gemm_h_kernel<<<gemmBlocks, 512, 0, stream>>>(
        XH, T1o, T1i, S2o, S2i, HR, T1oH, T1iH, S2oH, S2iH,
        wf_all + 2 * 30720, bh, H, ZB, out, N);
}

// Round 12
// 284.023 us; speedup vs baseline: 1.3157x; 1.0244x over previous
//
#include <hip/hip_runtime.h>

// DCRNN cell: 3x diffusion conv (fwd/bwd, K=3 Chebyshev) + GRU gating.
// N=50000 nodes, E=800000 edges, F_IN=32, F_OUT=64, fan=96.
// Round 12: Chebyshev fold into weights: S2=2*P*T1-XH replaced by plain
// U2=P*T1 with seg0-=(W02+W12), seg3/4*=2. Removes the 9.6MB/dir base
// re-read from both hop-2 gathers. HR computed from XH's bf16 H-part.

#define NTHREADS 256
#define BKT_BITS 10
#define BKT_NODES 1024
#define STG_CAP 32768   // per-bucket staging capacity (expected ~16.4K)

typedef unsigned short u16;
typedef unsigned int u32;
typedef unsigned long long u64;
typedef __attribute__((ext_vector_type(8))) short short8;   // 8 bf16 (4 VGPRs)
typedef __attribute__((ext_vector_type(4))) float f32x4;

__device__ __forceinline__ float sigmoidf_(float x) { return 1.f / (1.f + __expf(-x)); }
__device__ __forceinline__ float b2f_lo(u32 u) { return __uint_as_float(u << 16); }
__device__ __forceinline__ float b2f_hi(u32 u) { return __uint_as_float(u & 0xffff0000u); }
__device__ __forceinline__ u16 f2b(float f) {
    u32 u = __float_as_uint(f);
    return (u16)((u + 0x7fffu + ((u >> 16) & 1u)) >> 16);
}
__device__ __forceinline__ u32 pack2(float a, float b) {
    return (u32)f2b(a) | ((u32)f2b(b) << 16);
}

// ---------------------------------------------------------------- edge decode

__device__ __forceinline__ void load_edge(const int* ei, int e, int E, int i64,
                                          int& r, int& c) {
    if (i64) {
        const long long* p = (const long long*)ei;
        r = (int)p[e]; c = (int)p[E + e];
    } else {
        r = ei[e]; c = ei[E + e];
    }
}

__global__ void detect_i64_kernel(const int* ei, int n_check, int* flag) {
    __shared__ int any;
    if (threadIdx.x == 0) any = 0;
    __syncthreads();
    int local = 0;
    for (int i = threadIdx.x; i < n_check; i += blockDim.x)
        if (ei[2 * i + 1] != 0) local = 1;
    if (local) any = 1;  // benign race
    __syncthreads();
    if (threadIdx.x == 0) *flag = (any ? 0 : 1);  // 1 => int64 layout
}

// ---- Pass 1: bin edges into node-range buckets (both directions). ----
__global__ __launch_bounds__(1024) void bin_kernel(
    const int* __restrict__ ei, const int* __restrict__ flag, const float* __restrict__ ew,
    int* gCntF, int* gCntB, uint2* __restrict__ stgF, uint2* __restrict__ stgB,
    int E, int NB) {
    __shared__ int cF[64], cB[64], bF[64], bB[64];
    int t = threadIdx.x;
    if (t < NB) { cF[t] = 0; cB[t] = 0; }
    __syncthreads();
    int i64 = *flag;
    int r[4], c[4], e[4]; float w[4];
#pragma unroll
    for (int k = 0; k < 4; ++k) {
        e[k] = blockIdx.x * 4096 + k * 1024 + t;
        if (e[k] < E) {
            load_edge(ei, e[k], E, i64, r[k], c[k]);
            w[k] = ew[e[k]];
            atomicAdd(&cF[c[k] >> BKT_BITS], 1);
            atomicAdd(&cB[r[k] >> BKT_BITS], 1);
        }
    }
    __syncthreads();
    if (t < NB) bF[t] = atomicAdd(&gCntF[t], cF[t]);
    if (t >= 256 && t < 256 + NB) bB[t - 256] = atomicAdd(&gCntB[t - 256], cB[t - 256]);
    __syncthreads();
    if (t < NB) cF[t] = 0;                      // reuse as intra-block cursor
    if (t >= 256 && t < 256 + NB) cB[t - 256] = 0;
    __syncthreads();
#pragma unroll
    for (int k = 0; k < 4; ++k) {
        if (e[k] < E) {
            int jf = c[k] >> BKT_BITS;
            int pf = bF[jf] + atomicAdd(&cF[jf], 1);
            stgF[(size_t)jf * STG_CAP + pf] =
                make_uint2(__float_as_uint(w[k]), ((u32)r[k] << BKT_BITS) | (u32)(c[k] & (BKT_NODES - 1)));
            int jb = r[k] >> BKT_BITS;
            int pb = bB[jb] + atomicAdd(&cB[jb], 1);
            stgB[(size_t)jb * STG_CAP + pb] =
                make_uint2(__float_as_uint(w[k]), ((u32)c[k] << BKT_BITS) | (u32)(r[k] & (BKT_NODES - 1)));
        }
    }
}

// ---- tiny scan over bucket totals -> CSR region bases ----
__global__ void bktscan_kernel(const int* __restrict__ gCntF, const int* __restrict__ gCntB,
                               int* bBaseF, int* bBaseB, int* of, int* ob,
                               int NB, int N, int E) {
    if (threadIdx.x == 0) {
        int s = 0;
        for (int j = 0; j < NB; ++j) { bBaseF[j] = s; s += gCntF[j]; }
        bBaseF[NB] = s; of[N] = E;
    }
    if (threadIdx.x == 1) {
        int s = 0;
        for (int j = 0; j < NB; ++j) { bBaseB[j] = s; s += gCntB[j]; }
        bBaseB[NB] = s; ob[N] = E;
    }
}

// ---- Pass 2a: weighted degrees per bucket, accumulated in LDS. ----
__global__ __launch_bounds__(1024) void bktdeg_kernel(
    const uint2* __restrict__ stgF, const uint2* __restrict__ stgB,
    const int* __restrict__ gCntF, const int* __restrict__ gCntB,
    float* __restrict__ deg_in, float* __restrict__ deg_out, int N, int NB) {
    __shared__ float acc[BKT_NODES];
    int j = blockIdx.x, t = threadIdx.x;
    bool fwd = j < NB;
    int jb = fwd ? j : j - NB;
    acc[t] = 0.f;
    __syncthreads();
    const uint2* stg = (fwd ? stgF : stgB) + (size_t)jb * STG_CAP;
    int m = fwd ? gCntF[jb] : gCntB[jb];
    for (int i = t; i < m; i += 1024) {
        uint2 p = stg[i];
        atomicAdd(&acc[p.y & (BKT_NODES - 1)], __uint_as_float(p.x));
    }
    __syncthreads();
    int n = jb * BKT_NODES + t;
    if (n < N) { if (fwd) deg_in[n] = acc[t]; else deg_out[n] = acc[t]; }
}

// ---- Pass 2b: per-node offs + exact CSR payload (packed u32). ----
__global__ __launch_bounds__(1024) void bktcsr_kernel(
    const uint2* __restrict__ stgF, const uint2* __restrict__ stgB,
    const int* __restrict__ gCntF, const int* __restrict__ gCntB,
    const int* __restrict__ bBaseF, const int* __restrict__ bBaseB,
    const float* __restrict__ deg_in, const float* __restrict__ deg_out,
    int* __restrict__ of, int* __restrict__ ob,
    u32* __restrict__ pf, u32* __restrict__ pb, int N, int NB) {
    __shared__ int cnt[BKT_NODES], scn[BKT_NODES];
    int j = blockIdx.x, t = threadIdx.x;
    bool fwd = j < NB;
    int jb = fwd ? j : j - NB;
    const uint2* stg = (fwd ? stgF : stgB) + (size_t)jb * STG_CAP;
    int m = fwd ? gCntF[jb] : gCntB[jb];
    int base = fwd ? bBaseF[jb] : bBaseB[jb];
    const float* degS = fwd ? deg_out : deg_in;  // coeff divides by SRC-side degree
    cnt[t] = 0;
    __syncthreads();
    for (int i = t; i < m; i += 1024) atomicAdd(&cnt[stg[i].y & (BKT_NODES - 1)], 1);
    __syncthreads();
    int v = cnt[t];
    scn[t] = v;
    __syncthreads();
    for (int d = 1; d < 1024; d <<= 1) {
        int x = (t >= d) ? scn[t - d] : 0;
        __syncthreads();
        scn[t] += x;
        __syncthreads();
    }
    int ex = scn[t] - v;
    int n = jb * BKT_NODES + t;
    if (n < N) { if (fwd) of[n] = base + ex; else ob[n] = base + ex; }
    cnt[t] = ex;  // reuse as cursor
    __syncthreads();
    for (int i = t; i < m; i += 1024) {
        uint2 p = stg[i];
        int dl = p.y & (BKT_NODES - 1);
        int src = p.y >> BKT_BITS;
        float coeff = __uint_as_float(p.x) / degS[src];
        int pos = base + atomicAdd(&cnt[dl], 1);
        u32 packed = ((u32)src << 16) | (u32)f2b(coeff);  // assumes src < 65536
        if (fwd) pf[pos] = packed; else pb[pos] = packed;
    }
}

// XH = [X | H] in bf16. Each thread emits 8 bf16 (16B). N*12 chunks.
__global__ void build_xh_kernel(const float4* __restrict__ X4, const float4* __restrict__ H4,
                                uint4* __restrict__ XH, int N) {
    int idx = blockIdx.x * blockDim.x + threadIdx.x;
    if (idx >= N * 12) return;
    int n = idx / 12, c = idx % 12;
    float4 a, b;
    if (c < 4) { a = X4[n * 8 + c * 2]; b = X4[n * 8 + c * 2 + 1]; }
    else       { a = H4[n * 16 + (c - 4) * 2]; b = H4[n * 16 + (c - 4) * 2 + 1]; }
    uint4 o;
    o.x = pack2(a.x, a.y); o.y = pack2(a.z, a.w);
    o.z = pack2(b.x, b.y); o.w = pack2(b.z, b.w);
    XH[idx] = o;
}

#define GACC(vv, ww) \
    a0 += (ww) * b2f_lo((vv).x); a1 += (ww) * b2f_hi((vv).x); \
    a2 += (ww) * b2f_lo((vv).y); a3 += (ww) * b2f_hi((vv).y); \
    a4 += (ww) * b2f_lo((vv).z); a5 += (ww) * b2f_hi((vv).z); \
    a6 += (ww) * b2f_lo((vv).w); a7 += (ww) * b2f_hi((vv).w);

// Dual-direction bf16 gather, 96-col rows. blockDim = (12, 32). Unroll x4.
// out[n] = sum_e w[e] * x[src[e]]  (plain; Chebyshev fold lives in weights).
__global__ __launch_bounds__(384) void gather2_kernel(
    const uint4* __restrict__ xf, const uint4* __restrict__ xb,
    const int* __restrict__ offs_f, const u32* __restrict__ pf,
    const int* __restrict__ offs_b, const u32* __restrict__ pb,
    uint4* __restrict__ outf, uint4* __restrict__ outb, int N) {
    const uint4* x; const int* offs; const u32* pr; uint4* out;
    if (blockIdx.y == 0) { x = xf; offs = offs_f; pr = pf; out = outf; }
    else                 { x = xb; offs = offs_b; pr = pb; out = outb; }
    int n = blockIdx.x * 32 + threadIdx.y;
    if (n >= N) return;
    int c = threadIdx.x;  // 0..11
    int s0 = offs[n], s1 = offs[n + 1];
    float a0 = 0, a1 = 0, a2 = 0, a3 = 0, a4 = 0, a5 = 0, a6 = 0, a7 = 0;
    int o = s0;
    for (; o + 4 <= s1; o += 4) {
        u32 p0 = pr[o], p1 = pr[o + 1], p2 = pr[o + 2], p3 = pr[o + 3];
        uint4 v0 = x[(size_t)(p0 >> 16) * 12 + c];
        uint4 v1 = x[(size_t)(p1 >> 16) * 12 + c];
        uint4 v2 = x[(size_t)(p2 >> 16) * 12 + c];
        uint4 v3 = x[(size_t)(p3 >> 16) * 12 + c];
        float w0 = b2f_lo(p0), w1 = b2f_lo(p1), w2 = b2f_lo(p2), w3 = b2f_lo(p3);
        GACC(v0, w0) GACC(v1, w1) GACC(v2, w2) GACC(v3, w3)
    }
    for (; o < s1; ++o) {
        u32 p0 = pr[o];
        uint4 v0 = x[(size_t)(p0 >> 16) * 12 + c];
        float w0 = b2f_lo(p0);
        GACC(v0, w0)
    }
    size_t oi = (size_t)n * 12 + c;
    uint4 ov;
    ov.x = pack2(a0, a1); ov.y = pack2(a2, a3);
    ov.z = pack2(a4, a5); ov.w = pack2(a6, a7);
    out[oi] = ov;
}

// Dual-direction bf16 gather, 64-col rows (phase-H H-part). blockDim = (8, 48).
__global__ __launch_bounds__(384) void gather2h_kernel(
    const uint4* __restrict__ xf, const uint4* __restrict__ xb,
    const int* __restrict__ offs_f, const u32* __restrict__ pf,
    const int* __restrict__ offs_b, const u32* __restrict__ pb,
    uint4* __restrict__ outf, uint4* __restrict__ outb, int N) {
    const uint4* x; const int* offs; const u32* pr; uint4* out;
    if (blockIdx.y == 0) { x = xf; offs = offs_f; pr = pf; out = outf; }
    else                 { x = xb; offs = offs_b; pr = pb; out = outb; }
    int n = blockIdx.x * 48 + threadIdx.y;
    if (n >= N) return;
    int c = threadIdx.x;  // 0..7
    int s0 = offs[n], s1 = offs[n + 1];
    float a0 = 0, a1 = 0, a2 = 0, a3 = 0, a4 = 0, a5 = 0, a6 = 0, a7 = 0;
    int o = s0;
    for (; o + 4 <= s1; o += 4) {
        u32 p0 = pr[o], p1 = pr[o + 1], p2 = pr[o + 2], p3 = pr[o + 3];
        uint4 v0 = x[(size_t)(p0 >> 16) * 8 + c];
        uint4 v1 = x[(size_t)(p1 >> 16) * 8 + c];
        uint4 v2 = x[(size_t)(p2 >> 16) * 8 + c];
        uint4 v3 = x[(size_t)(p3 >> 16) * 8 + c];
        float w0 = b2f_lo(p0), w1 = b2f_lo(p1), w2 = b2f_lo(p2), w3 = b2f_lo(p3);
        GACC(v0, w0) GACC(v1, w1) GACC(v2, w2) GACC(v3, w3)
    }
    for (; o < s1; ++o) {
        u32 p0 = pr[o];
        uint4 v0 = x[(size_t)(p0 >> 16) * 8 + c];
        float w0 = b2f_lo(p0);
        GACC(v0, w0)
    }
    size_t oi = (size_t)n * 8 + c;
    uint4 ov;
    ov.x = pack2(a0, a1); ov.y = pack2(a2, a3);
    ov.z = pack2(a4, a5); ov.w = pack2(a6, a7);
    out[oi] = ov;
}

// Fuse + swizzle gate weights into MFMA-fragment-linear bf16, with the
// Chebyshev fold: seg0 = W00+W10-W02-W12, seg1 = W01, seg2 = W11,
// seg3 = 2*W02, seg4 = 2*W12. One thread per element.
__global__ void prep_weights_kernel(const float* __restrict__ Wz, const float* __restrict__ Wr,
                                    const float* __restrict__ Wh, u16* __restrict__ wf_all) {
    const int KS = 96 * 64;
    int idx = blockIdx.x * blockDim.x + threadIdx.x;
    if (idx >= 3 * 30720) return;
    int g = idx / 30720, i = idx - g * 30720;
    const float* W = (g == 0) ? Wz : (g == 1) ? Wr : Wh;
    int j = i & 7, lane = (i >> 3) & 63, ct = (i >> 9) & 3, kt = i >> 11;
    int k = kt * 32 + (lane >> 4) * 8 + j;
    int col = ct * 16 + (lane & 15);
    int m = k / 96, fr = k - m * 96;
    int e = fr * 64 + col;
    float v;
    if (m == 0)      v = W[e] + W[3 * KS + e] - W[2 * KS + e] - W[5 * KS + e];
    else if (m == 1) v = W[1 * KS + e];
    else if (m == 2) v = W[4 * KS + e];
    else if (m == 3) v = 2.f * W[2 * KS + e];
    else             v = 2.f * W[5 * KS + e];
    wf_all[idx] = f2b(v);
}

// Fused Z+R GEMM: A (5 matrices, [N,96]) read ONCE into registers; two-phase
// LDS weight staging. Writes Z (bf16) and HR = Hb*sigmoid(accR) (bf16, Hb
// taken from XH's bf16 H-columns).
__global__ __launch_bounds__(512) void gemm_zr_kernel(
    const u16* __restrict__ A0, const u16* __restrict__ A1, const u16* __restrict__ A2,
    const u16* __restrict__ A3, const u16* __restrict__ A4,
    const u16* __restrict__ wfZ, const u16* __restrict__ wfR,
    const float* __restrict__ bz, const float* __restrict__ br,
    u16* __restrict__ ZB, u16* __restrict__ HR, int N) {
    __shared__ u16 wl[30720];  // 61440 B -> 2 blocks/CU
    int t = threadIdx.x;
    {
        const uint4* src = (const uint4*)wfZ;
        uint4* dst = (uint4*)wl;
        for (int i = t; i < 3840; i += 512) dst[i] = src[i];
    }

    int lane = t & 63, w = t >> 6;
    int rowBase = blockIdx.x * 128 + w * 16;
    int arow = rowBase + (lane & 15);
    int cf = (lane >> 4) * 8;
    int rsub = (lane >> 4) * 4;

    // Load all 15 A fragments (held across both phases).
    short8 afr[15];
    const u16* As[5] = {A0, A1, A2, A3, A4};
#pragma unroll
    for (int m = 0; m < 5; ++m) {
        const u16* a = As[m] + (size_t)arow * 96 + cf;
        afr[m * 3 + 0] = *(const short8*)(a);
        afr[m * 3 + 1] = *(const short8*)(a + 32);
        afr[m * 3 + 2] = *(const short8*)(a + 64);
    }
    __syncthreads();

    // ---- phase Z ----
    {
        f32x4 acc[4];
#pragma unroll
        for (int ct = 0; ct < 4; ++ct) {
            float b = bz[ct * 16 + (lane & 15)];
            acc[ct] = (f32x4){b, b, b, b};
        }
#pragma unroll
        for (int ktg = 0; ktg < 15; ++ktg)
#pragma unroll
            for (int ct = 0; ct < 4; ++ct) {
                short8 bfrag = *(const short8*)(&wl[((ktg * 4 + ct) * 64 + lane) * 8]);
                acc[ct] = __builtin_amdgcn_mfma_f32_16x16x32_bf16(afr[ktg], bfrag, acc[ct], 0, 0, 0);
            }
#pragma unroll
        for (int ct = 0; ct < 4; ++ct) {
            int col = ct * 16 + (lane & 15);
#pragma unroll
            for (int j = 0; j < 4; ++j) {
                int grow = rowBase + rsub + j;
                if (grow >= N) continue;
                ZB[(size_t)grow * 64 + col] = f2b(sigmoidf_(acc[ct][j]));
            }
        }
    }
    __syncthreads();  // all reads of wl (Z weights) done
    {
        const uint4* src = (const uint4*)wfR;
        uint4* dst = (uint4*)wl;
        for (int i = t; i < 3840; i += 512) dst[i] = src[i];
    }
    __syncthreads();

    // ---- phase R ----
    {
        f32x4 acc[4];
#pragma unroll
        for (int ct = 0; ct < 4; ++ct) {
            float b = br[ct * 16 + (lane & 15)];
            acc[ct] = (f32x4){b, b, b, b};
        }
#pragma unroll
        for (int ktg = 0; ktg < 15; ++ktg)
#pragma unroll
            for (int ct = 0; ct < 4; ++ct) {
                short8 bfrag = *(const short8*)(&wl[((ktg * 4 + ct) * 64 + lane) * 8]);
                acc[ct] = __builtin_amdgcn_mfma_f32_16x16x32_bf16(afr[ktg], bfrag, acc[ct], 0, 0, 0);
            }
#pragma unroll
        for (int ct = 0; ct < 4; ++ct) {
            int col = ct * 16 + (lane & 15);
#pragma unroll
            for (int j = 0; j < 4; ++j) {
                int grow = rowBase + rsub + j;
                if (grow >= N) continue;
                // Hb from XH's bf16 H-columns (A0 = XH)
                float hb = b2f_lo((u32)A0[(size_t)grow * 96 + 32 + col]);
                HR[(size_t)grow * 64 + col] = f2b(hb * sigmoidf_(acc[ct][j]));
            }
        }
    }
}

// H~ GEMM + GRU combine: A split (X-part stride 96 from ZR buffers, H-part
// stride 64). out = Z*H + (1-Z)*tanh(acc), Z read as bf16, H f32.
__global__ __launch_bounds__(512) void gemm_h_kernel(
    const u16* __restrict__ AX0, const u16* __restrict__ AX1, const u16* __restrict__ AX2,
    const u16* __restrict__ AX3, const u16* __restrict__ AX4,
    const u16* __restrict__ AH0, const u16* __restrict__ AH1, const u16* __restrict__ AH2,
    const u16* __restrict__ AH3, const u16* __restrict__ AH4,
    const u16* __restrict__ wfrag, const float* __restrict__ bias,
    const float* __restrict__ H, const u16* __restrict__ ZB,
    float* __restrict__ Out, int N) {
    __shared__ u16 wl[30720];
    int t = threadIdx.x;
    {
        const uint4* src = (const uint4*)wfrag;
        uint4* dst = (uint4*)wl;
        for (int i = t; i < 3840; i += 512) dst[i] = src[i];
    }
    __syncthreads();

    int lane = t & 63, w = t >> 6;
    int rowBase = blockIdx.x * 128 + w * 16;
    int arow = rowBase + (lane & 15);
    int cf = (lane >> 4) * 8;

    f32x4 acc[4];
#pragma unroll
    for (int ct = 0; ct < 4; ++ct) {
        float b = bias[ct * 16 + (lane & 15)];
        acc[ct] = (f32x4){b, b, b, b};
    }

    const u16* AXs[5] = {AX0, AX1, AX2, AX3, AX4};
    const u16* AHs[5] = {AH0, AH1, AH2, AH3, AH4};
#pragma unroll
    for (int m = 0; m < 5; ++m) {
        const u16* ax = AXs[m] + (size_t)arow * 96 + cf;
        const u16* ah = AHs[m] + (size_t)arow * 64 + cf;
#pragma unroll
        for (int k3 = 0; k3 < 3; ++k3) {
            short8 a = (k3 == 0) ? *(const short8*)ax
                                 : *(const short8*)(ah + (k3 - 1) * 32);
            int ktg = m * 3 + k3;
#pragma unroll
            for (int ct = 0; ct < 4; ++ct) {
                short8 b = *(const short8*)(&wl[((ktg * 4 + ct) * 64 + lane) * 8]);
                acc[ct] = __builtin_amdgcn_mfma_f32_16x16x32_bf16(a, b, acc[ct], 0, 0, 0);
            }
        }
    }

    int rsub = (lane >> 4) * 4;
#pragma unroll
    for (int ct = 0; ct < 4; ++ct) {
        int col = ct * 16 + (lane & 15);
#pragma unroll
        for (int j = 0; j < 4; ++j) {
            int grow = rowBase + rsub + j;
            if (grow >= N) continue;
            size_t bi = (size_t)grow * 64 + col;
            float z = b2f_lo((u32)ZB[bi]);
            Out[bi] = z * H[bi] + (1.f - z) * tanhf(acc[ct][j]);
        }
    }
}

// ---------------------------------------------------------------- launch

extern "C" void kernel_launch(void* const* d_in, const int* in_sizes, int n_in,
                              void* d_out, int out_size, void* d_ws, size_t ws_size,
                              hipStream_t stream) {
    const float* X  = (const float*)d_in[0];
    const int*   ei = (const int*)d_in[1];
    const float* ew = (const float*)d_in[2];
    const float* H  = (const float*)d_in[3];
    const float* Wz = (const float*)d_in[4];
    const float* bz = (const float*)d_in[5];
    const float* Wr = (const float*)d_in[6];
    const float* br = (const float*)d_in[7];
    const float* Wh = (const float*)d_in[8];
    const float* bh = (const float*)d_in[9];
    float* out = (float*)d_out;

    const int N = in_sizes[0] / 32;   // 50000
    const int E = in_sizes[2];        // 800000
    const int NB = (N + BKT_NODES - 1) >> BKT_BITS;  // 49 (code assumes NB <= 64)

    // ---- workspace carve (256B aligned) ----
    char* wp = (char*)d_ws;
    auto alloc = [&](size_t nbytes) -> void* {
        void* p = (void*)wp;
        wp += (nbytes + 255) & ~(size_t)255;
        return p;
    };
    u16* XH   = (u16*)alloc((size_t)N * 96 * 2);   // [X|H], stays intact
    u16* T1o  = (u16*)alloc((size_t)N * 96 * 2);
    u16* T1i  = (u16*)alloc((size_t)N * 96 * 2);
    u16* U2o  = (u16*)alloc((size_t)N * 96 * 2);   // plain P*T1 (fold in W)
    u16* U2i  = (u16*)alloc((size_t)N * 96 * 2);
    u16* HR   = (u16*)alloc((size_t)N * 64 * 2);   // H*R (phase-H H-part)
    u16* T1oH = (u16*)alloc((size_t)N * 64 * 2);
    u16* T1iH = (u16*)alloc((size_t)N * 64 * 2);
    u16* U2oH = (u16*)alloc((size_t)N * 64 * 2);
    u16* U2iH = (u16*)alloc((size_t)N * 64 * 2);
    u16* ZB   = (u16*)alloc((size_t)N * 64 * 2);   // Z gate, bf16
    float* deg_in  = (float*)alloc((size_t)N * 4);
    float* deg_out = (float*)alloc((size_t)N * 4);
    int* offs_f = (int*)alloc((size_t)(N + 1) * 4);
    int* offs_b = (int*)alloc((size_t)(N + 1) * 4);
    u32* pair_f = (u32*)alloc((size_t)E * 4);
    u32* pair_b = (u32*)alloc((size_t)E * 4);
    uint2* stgF = (uint2*)alloc((size_t)NB * STG_CAP * 8);
    uint2* stgB = (uint2*)alloc((size_t)NB * STG_CAP * 8);
    u16* wf_all = (u16*)alloc((size_t)3 * 30720 * 2);
    int* gCntF  = (int*)alloc(64 * 4);
    int* gCntB  = (int*)alloc(64 * 4);
    int* bBaseF = (int*)alloc(65 * 4);
    int* bBaseB = (int*)alloc(65 * 4);
    int* flag   = (int*)alloc(256);

    const int xhBlocks = (N * 12 + NTHREADS - 1) / NTHREADS;
    const int gemmBlocks = (N + 127) / 128;
    const int binBlocks = (E + 4095) / 4096;
    const int pwBlocks = (3 * 30720 + NTHREADS - 1) / NTHREADS;
    dim3 gatherBlock(12, 32);
    dim3 gatherGrid((N + 31) / 32, 2);
    dim3 gatherHBlock(8, 48);
    dim3 gatherHGrid((N + 47) / 48, 2);

    // ---- edge preprocessing (bucketed CSR build) ----
    hipMemsetAsync(gCntF, 0, 64 * 4, stream);
    hipMemsetAsync(gCntB, 0, 64 * 4, stream);

    detect_i64_kernel<<<1, 256, 0, stream>>>(ei, E < 8192 ? E : 8192, flag);
    prep_weights_kernel<<<pwBlocks, NTHREADS, 0, stream>>>(Wz, Wr, Wh, wf_all);
    bin_kernel<<<binBlocks, 1024, 0, stream>>>(ei, flag, ew, gCntF, gCntB, stgF, stgB, E, NB);
    bktscan_kernel<<<1, 64, 0, stream>>>(gCntF, gCntB, bBaseF, bBaseB, offs_f, offs_b, NB, N, E);
    bktdeg_kernel<<<2 * NB, 1024, 0, stream>>>(stgF, stgB, gCntF, gCntB, deg_in, deg_out, N, NB);
    bktcsr_kernel<<<2 * NB, 1024, 0, stream>>>(stgF, stgB, gCntF, gCntB, bBaseF, bBaseB,
                                               deg_in, deg_out, offs_f, offs_b,
                                               pair_f, pair_b, N, NB);

    // ---- phase ZR: shared T matrices on XH = [X|H] (96-col gathers) ----
    build_xh_kernel<<<xhBlocks, NTHREADS, 0, stream>>>((const float4*)X, (const float4*)H,
                                                       (uint4*)XH, N);
    gather2_kernel<<<gatherGrid, gatherBlock, 0, stream>>>(
        (const uint4*)XH, (const uint4*)XH, offs_f, pair_f, offs_b, pair_b,
        (uint4*)T1o, (uint4*)T1i, N);
    gather2_kernel<<<gatherGrid, gatherBlock, 0, stream>>>(
        (const uint4*)T1o, (const uint4*)T1i, offs_f, pair_f, offs_b, pair_b,
        (uint4*)U2o, (uint4*)U2i, N);

    // Fused Z+R gates (A read once): Z -> ZB (bf16), HR = Hb*sigmoid (bf16)
    gemm_zr_kernel<<<gemmBlocks, 512, 0, stream>>>(
        XH, T1o, T1i, U2o, U2i, wf_all, wf_all + 30720, bz, br, ZB, HR, N);

    // ---- phase H: propagate only the 64-col H*R part (X-part reused from ZR) ----
    gather2h_kernel<<<gatherHGrid, gatherHBlock, 0, stream>>>(
        (const uint4*)HR, (const uint4*)HR, offs_f, pair_f, offs_b, pair_b,
        (uint4*)T1oH, (uint4*)T1iH, N);
    gather2h_kernel<<<gatherHGrid, gatherHBlock, 0, stream>>>(
        (const uint4*)T1oH, (const uint4*)T1iH, offs_f, pair_f, offs_b, pair_b,
        (uint4*)U2oH, (uint4*)U2iH, N);

    // H~ gate + GRU combine fused; A = [X-part from ZR buffers | H-part 64-col]
    gemm_h_kernel<<<gemmBlocks, 512, 0, stream>>>(
        XH, T1o, T1i, U2o, U2i, HR, T1oH, T1iH, U2oH, U2iH,
        wf_all + 2 * 30720, bh, H, ZB, out, N);
}

// Round 13
// 282.087 us; speedup vs baseline: 1.3247x; 1.0069x over previous
//
#include <hip/hip_runtime.h>

// DCRNN cell: 3x diffusion conv (fwd/bwd, K=3 Chebyshev) + GRU gating.
// N=50000 nodes, E=800000 edges, F_IN=32, F_OUT=64, fan=96.
// Round 13: direction->XCD-half swizzle in gathers (bid%8 round-robins XCDs;
// r>=4 -> bwd). Hop-2 dispatches read different sources per direction, so
// this halves the per-XCD L2 working set (19.2 -> 9.6MB).

#define NTHREADS 256
#define BKT_BITS 10
#define BKT_NODES 1024
#define STG_CAP 32768   // per-bucket staging capacity (expected ~16.4K)

typedef unsigned short u16;
typedef unsigned int u32;
typedef unsigned long long u64;
typedef __attribute__((ext_vector_type(8))) short short8;   // 8 bf16 (4 VGPRs)
typedef __attribute__((ext_vector_type(4))) float f32x4;

__device__ __forceinline__ float sigmoidf_(float x) { return 1.f / (1.f + __expf(-x)); }
__device__ __forceinline__ float b2f_lo(u32 u) { return __uint_as_float(u << 16); }
__device__ __forceinline__ float b2f_hi(u32 u) { return __uint_as_float(u & 0xffff0000u); }
__device__ __forceinline__ u16 f2b(float f) {
    u32 u = __float_as_uint(f);
    return (u16)((u + 0x7fffu + ((u >> 16) & 1u)) >> 16);
}
__device__ __forceinline__ u32 pack2(float a, float b) {
    return (u32)f2b(a) | ((u32)f2b(b) << 16);
}

// ---------------------------------------------------------------- edge decode

__device__ __forceinline__ void load_edge(const int* ei, int e, int E, int i64,
                                          int& r, int& c) {
    if (i64) {
        const long long* p = (const long long*)ei;
        r = (int)p[e]; c = (int)p[E + e];
    } else {
        r = ei[e]; c = ei[E + e];
    }
}

__global__ void detect_i64_kernel(const int* ei, int n_check, int* flag) {
    __shared__ int any;
    if (threadIdx.x == 0) any = 0;
    __syncthreads();
    int local = 0;
    for (int i = threadIdx.x; i < n_check; i += blockDim.x)
        if (ei[2 * i + 1] != 0) local = 1;
    if (local) any = 1;  // benign race
    __syncthreads();
    if (threadIdx.x == 0) *flag = (any ? 0 : 1);  // 1 => int64 layout
}

// ---- Pass 1: bin edges into node-range buckets (both directions). ----
__global__ __launch_bounds__(1024) void bin_kernel(
    const int* __restrict__ ei, const int* __restrict__ flag, const float* __restrict__ ew,
    int* gCntF, int* gCntB, uint2* __restrict__ stgF, uint2* __restrict__ stgB,
    int E, int NB) {
    __shared__ int cF[64], cB[64], bF[64], bB[64];
    int t = threadIdx.x;
    if (t < NB) { cF[t] = 0; cB[t] = 0; }
    __syncthreads();
    int i64 = *flag;
    int r[4], c[4], e[4]; float w[4];
#pragma unroll
    for (int k = 0; k < 4; ++k) {
        e[k] = blockIdx.x * 4096 + k * 1024 + t;
        if (e[k] < E) {
            load_edge(ei, e[k], E, i64, r[k], c[k]);
            w[k] = ew[e[k]];
            atomicAdd(&cF[c[k] >> BKT_BITS], 1);
            atomicAdd(&cB[r[k] >> BKT_BITS], 1);
        }
    }
    __syncthreads();
    if (t < NB) bF[t] = atomicAdd(&gCntF[t], cF[t]);
    if (t >= 256 && t < 256 + NB) bB[t - 256] = atomicAdd(&gCntB[t - 256], cB[t - 256]);
    __syncthreads();
    if (t < NB) cF[t] = 0;                      // reuse as intra-block cursor
    if (t >= 256 && t < 256 + NB) cB[t - 256] = 0;
    __syncthreads();
#pragma unroll
    for (int k = 0; k < 4; ++k) {
        if (e[k] < E) {
            int jf = c[k] >> BKT_BITS;
            int pf = bF[jf] + atomicAdd(&cF[jf], 1);
            stgF[(size_t)jf * STG_CAP + pf] =
                make_uint2(__float_as_uint(w[k]), ((u32)r[k] << BKT_BITS) | (u32)(c[k] & (BKT_NODES - 1)));
            int jb = r[k] >> BKT_BITS;
            int pb = bB[jb] + atomicAdd(&cB[jb], 1);
            stgB[(size_t)jb * STG_CAP + pb] =
                make_uint2(__float_as_uint(w[k]), ((u32)c[k] << BKT_BITS) | (u32)(r[k] & (BKT_NODES - 1)));
        }
    }
}

// ---- tiny scan over bucket totals -> CSR region bases ----
__global__ void bktscan_kernel(const int* __restrict__ gCntF, const int* __restrict__ gCntB,
                               int* bBaseF, int* bBaseB, int* of, int* ob,
                               int NB, int N, int E) {
    if (threadIdx.x == 0) {
        int s = 0;
        for (int j = 0; j < NB; ++j) { bBaseF[j] = s; s += gCntF[j]; }
        bBaseF[NB] = s; of[N] = E;
    }
    if (threadIdx.x == 1) {
        int s = 0;
        for (int j = 0; j < NB; ++j) { bBaseB[j] = s; s += gCntB[j]; }
        bBaseB[NB] = s; ob[N] = E;
    }
}

// ---- Pass 2a: weighted degrees per bucket, accumulated in LDS. ----
__global__ __launch_bounds__(1024) void bktdeg_kernel(
    const uint2* __restrict__ stgF, const uint2* __restrict__ stgB,
    const int* __restrict__ gCntF, const int* __restrict__ gCntB,
    float* __restrict__ deg_in, float* __restrict__ deg_out, int N, int NB) {
    __shared__ float acc[BKT_NODES];
    int j = blockIdx.x, t = threadIdx.x;
    bool fwd = j < NB;
    int jb = fwd ? j : j - NB;
    acc[t] = 0.f;
    __syncthreads();
    const uint2* stg = (fwd ? stgF : stgB) + (size_t)jb * STG_CAP;
    int m = fwd ? gCntF[jb] : gCntB[jb];
    for (int i = t; i < m; i += 1024) {
        uint2 p = stg[i];
        atomicAdd(&acc[p.y & (BKT_NODES - 1)], __uint_as_float(p.x));
    }
    __syncthreads();
    int n = jb * BKT_NODES + t;
    if (n < N) { if (fwd) deg_in[n] = acc[t]; else deg_out[n] = acc[t]; }
}

// ---- Pass 2b: per-node offs + exact CSR payload (packed u32). ----
__global__ __launch_bounds__(1024) void bktcsr_kernel(
    const uint2* __restrict__ stgF, const uint2* __restrict__ stgB,
    const int* __restrict__ gCntF, const int* __restrict__ gCntB,
    const int* __restrict__ bBaseF, const int* __restrict__ bBaseB,
    const float* __restrict__ deg_in, const float* __restrict__ deg_out,
    int* __restrict__ of, int* __restrict__ ob,
    u32* __restrict__ pf, u32* __restrict__ pb, int N, int NB) {
    __shared__ int cnt[BKT_NODES], scn[BKT_NODES];
    int j = blockIdx.x, t = threadIdx.x;
    bool fwd = j < NB;
    int jb = fwd ? j : j - NB;
    const uint2* stg = (fwd ? stgF : stgB) + (size_t)jb * STG_CAP;
    int m = fwd ? gCntF[jb] : gCntB[jb];
    int base = fwd ? bBaseF[jb] : bBaseB[jb];
    const float* degS = fwd ? deg_out : deg_in;  // coeff divides by SRC-side degree
    cnt[t] = 0;
    __syncthreads();
    for (int i = t; i < m; i += 1024) atomicAdd(&cnt[stg[i].y & (BKT_NODES - 1)], 1);
    __syncthreads();
    int v = cnt[t];
    scn[t] = v;
    __syncthreads();
    for (int d = 1; d < 1024; d <<= 1) {
        int x = (t >= d) ? scn[t - d] : 0;
        __syncthreads();
        scn[t] += x;
        __syncthreads();
    }
    int ex = scn[t] - v;
    int n = jb * BKT_NODES + t;
    if (n < N) { if (fwd) of[n] = base + ex; else ob[n] = base + ex; }
    cnt[t] = ex;  // reuse as cursor
    __syncthreads();
    for (int i = t; i < m; i += 1024) {
        uint2 p = stg[i];
        int dl = p.y & (BKT_NODES - 1);
        int src = p.y >> BKT_BITS;
        float coeff = __uint_as_float(p.x) / degS[src];
        int pos = base + atomicAdd(&cnt[dl], 1);
        u32 packed = ((u32)src << 16) | (u32)f2b(coeff);  // assumes src < 65536
        if (fwd) pf[pos] = packed; else pb[pos] = packed;
    }
}

// XH = [X | H] in bf16. Each thread emits 8 bf16 (16B). N*12 chunks.
__global__ void build_xh_kernel(const float4* __restrict__ X4, const float4* __restrict__ H4,
                                uint4* __restrict__ XH, int N) {
    int idx = blockIdx.x * blockDim.x + threadIdx.x;
    if (idx >= N * 12) return;
    int n = idx / 12, c = idx % 12;
    float4 a, b;
    if (c < 4) { a = X4[n * 8 + c * 2]; b = X4[n * 8 + c * 2 + 1]; }
    else       { a = H4[n * 16 + (c - 4) * 2]; b = H4[n * 16 + (c - 4) * 2 + 1]; }
    uint4 o;
    o.x = pack2(a.x, a.y); o.y = pack2(a.z, a.w);
    o.z = pack2(b.x, b.y); o.w = pack2(b.z, b.w);
    XH[idx] = o;
}

#define GACC(vv, ww) \
    a0 += (ww) * b2f_lo((vv).x); a1 += (ww) * b2f_hi((vv).x); \
    a2 += (ww) * b2f_lo((vv).y); a3 += (ww) * b2f_hi((vv).y); \
    a4 += (ww) * b2f_lo((vv).z); a5 += (ww) * b2f_hi((vv).z); \
    a6 += (ww) * b2f_lo((vv).w); a7 += (ww) * b2f_hi((vv).w);

// Dual-direction bf16 gather, 96-col rows. blockDim = (12, 32). Unroll x4.
// 1D grid with direction->XCD-half swizzle: r = bid & 7; dir = r >= 4;
// nodeblk = (bid>>3)*4 + (r&3). bid%8 round-robins XCDs, so each XCD runs
// only one direction -> per-XCD L2 working set halves on hop-2.
__global__ __launch_bounds__(384) void gather2_kernel(
    const uint4* __restrict__ xf, const uint4* __restrict__ xb,
    const int* __restrict__ offs_f, const u32* __restrict__ pf,
    const int* __restrict__ offs_b, const u32* __restrict__ pb,
    uint4* __restrict__ outf, uint4* __restrict__ outb, int N) {
    int bid = blockIdx.x;
    int rb = bid & 7;
    int dir = rb >> 2;
    int nblk = (bid >> 3) * 4 + (rb & 3);
    int n = nblk * 32 + threadIdx.y;
    if (n >= N) return;
    const uint4* x; const int* offs; const u32* pr; uint4* out;
    if (dir == 0) { x = xf; offs = offs_f; pr = pf; out = outf; }
    else          { x = xb; offs = offs_b; pr = pb; out = outb; }
    int c = threadIdx.x;  // 0..11
    int s0 = offs[n], s1 = offs[n + 1];
    float a0 = 0, a1 = 0, a2 = 0, a3 = 0, a4 = 0, a5 = 0, a6 = 0, a7 = 0;
    int o = s0;
    for (; o + 4 <= s1; o += 4) {
        u32 p0 = pr[o], p1 = pr[o + 1], p2 = pr[o + 2], p3 = pr[o + 3];
        uint4 v0 = x[(size_t)(p0 >> 16) * 12 + c];
        uint4 v1 = x[(size_t)(p1 >> 16) * 12 + c];
        uint4 v2 = x[(size_t)(p2 >> 16) * 12 + c];
        uint4 v3 = x[(size_t)(p3 >> 16) * 12 + c];
        float w0 = b2f_lo(p0), w1 = b2f_lo(p1), w2 = b2f_lo(p2), w3 = b2f_lo(p3);
        GACC(v0, w0) GACC(v1, w1) GACC(v2, w2) GACC(v3, w3)
    }
    for (; o < s1; ++o) {
        u32 p0 = pr[o];
        uint4 v0 = x[(size_t)(p0 >> 16) * 12 + c];
        float w0 = b2f_lo(p0);
        GACC(v0, w0)
    }
    size_t oi = (size_t)n * 12 + c;
    uint4 ov;
    ov.x = pack2(a0, a1); ov.y = pack2(a2, a3);
    ov.z = pack2(a4, a5); ov.w = pack2(a6, a7);
    out[oi] = ov;
}

// Dual-direction bf16 gather, 64-col rows (phase-H H-part). blockDim = (8, 48).
// Same direction->XCD-half swizzle.
__global__ __launch_bounds__(384) void gather2h_kernel(
    const uint4* __restrict__ xf, const uint4* __restrict__ xb,
    const int* __restrict__ offs_f, const u32* __restrict__ pf,
    const int* __restrict__ offs_b, const u32* __restrict__ pb,
    uint4* __restrict__ outf, uint4* __restrict__ outb, int N) {
    int bid = blockIdx.x;
    int rb = bid & 7;
    int dir = rb >> 2;
    int nblk = (bid >> 3) * 4 + (rb & 3);
    int n = nblk * 48 + threadIdx.y;
    if (n >= N) return;
    const uint4* x; const int* offs; const u32* pr; uint4* out;
    if (dir == 0) { x = xf; offs = offs_f; pr = pf; out = outf; }
    else          { x = xb; offs = offs_b; pr = pb; out = outb; }
    int c = threadIdx.x;  // 0..7
    int s0 = offs[n], s1 = offs[n + 1];
    float a0 = 0, a1 = 0, a2 = 0, a3 = 0, a4 = 0, a5 = 0, a6 = 0, a7 = 0;
    int o = s0;
    for (; o + 4 <= s1; o += 4) {
        u32 p0 = pr[o], p1 = pr[o + 1], p2 = pr[o + 2], p3 = pr[o + 3];
        uint4 v0 = x[(size_t)(p0 >> 16) * 8 + c];
        uint4 v1 = x[(size_t)(p1 >> 16) * 8 + c];
        uint4 v2 = x[(size_t)(p2 >> 16) * 8 + c];
        uint4 v3 = x[(size_t)(p3 >> 16) * 8 + c];
        float w0 = b2f_lo(p0), w1 = b2f_lo(p1), w2 = b2f_lo(p2), w3 = b2f_lo(p3);
        GACC(v0, w0) GACC(v1, w1) GACC(v2, w2) GACC(v3, w3)
    }
    for (; o < s1; ++o) {
        u32 p0 = pr[o];
        uint4 v0 = x[(size_t)(p0 >> 16) * 8 + c];
        float w0 = b2f_lo(p0);
        GACC(v0, w0)
    }
    size_t oi = (size_t)n * 8 + c;
    uint4 ov;
    ov.x = pack2(a0, a1); ov.y = pack2(a2, a3);
    ov.z = pack2(a4, a5); ov.w = pack2(a6, a7);
    out[oi] = ov;
}

// Fuse + swizzle gate weights into MFMA-fragment-linear bf16, with the
// Chebyshev fold: seg0 = W00+W10-W02-W12, seg1 = W01, seg2 = W11,
// seg3 = 2*W02, seg4 = 2*W12. One thread per element.
__global__ void prep_weights_kernel(const float* __restrict__ Wz, const float* __restrict__ Wr,
                                    const float* __restrict__ Wh, u16* __restrict__ wf_all) {
    const int KS = 96 * 64;
    int idx = blockIdx.x * blockDim.x + threadIdx.x;
    if (idx >= 3 * 30720) return;
    int g = idx / 30720, i = idx - g * 30720;
    const float* W = (g == 0) ? Wz : (g == 1) ? Wr : Wh;
    int j = i & 7, lane = (i >> 3) & 63, ct = (i >> 9) & 3, kt = i >> 11;
    int k = kt * 32 + (lane >> 4) * 8 + j;
    int col = ct * 16 + (lane & 15);
    int m = k / 96, fr = k - m * 96;
    int e = fr * 64 + col;
    float v;
    if (m == 0)      v = W[e] + W[3 * KS + e] - W[2 * KS + e] - W[5 * KS + e];
    else if (m == 1) v = W[1 * KS + e];
    else if (m == 2) v = W[4 * KS + e];
    else if (m == 3) v = 2.f * W[2 * KS + e];
    else             v = 2.f * W[5 * KS + e];
    wf_all[idx] = f2b(v);
}

// Fused Z+R GEMM: A (5 matrices, [N,96]) read ONCE into registers; two-phase
// LDS weight staging. Writes Z (bf16) and HR = Hb*sigmoid(accR) (bf16, Hb
// taken from XH's bf16 H-columns).
__global__ __launch_bounds__(512) void gemm_zr_kernel(
    const u16* __restrict__ A0, const u16* __restrict__ A1, const u16* __restrict__ A2,
    const u16* __restrict__ A3, const u16* __restrict__ A4,
    const u16* __restrict__ wfZ, const u16* __restrict__ wfR,
    const float* __restrict__ bz, const float* __restrict__ br,
    u16* __restrict__ ZB, u16* __restrict__ HR, int N) {
    __shared__ u16 wl[30720];  // 61440 B -> 2 blocks/CU
    int t = threadIdx.x;
    {
        const uint4* src = (const uint4*)wfZ;
        uint4* dst = (uint4*)wl;
        for (int i = t; i < 3840; i += 512) dst[i] = src[i];
    }

    int lane = t & 63, w = t >> 6;
    int rowBase = blockIdx.x * 128 + w * 16;
    int arow = rowBase + (lane & 15);
    int cf = (lane >> 4) * 8;
    int rsub = (lane >> 4) * 4;

    // Load all 15 A fragments (held across both phases).
    short8 afr[15];
    const u16* As[5] = {A0, A1, A2, A3, A4};
#pragma unroll
    for (int m = 0; m < 5; ++m) {
        const u16* a = As[m] + (size_t)arow * 96 + cf;
        afr[m * 3 + 0] = *(const short8*)(a);
        afr[m * 3 + 1] = *(const short8*)(a + 32);
        afr[m * 3 + 2] = *(const short8*)(a + 64);
    }
    __syncthreads();

    // ---- phase Z ----
    {
        f32x4 acc[4];
#pragma unroll
        for (int ct = 0; ct < 4; ++ct) {
            float b = bz[ct * 16 + (lane & 15)];
            acc[ct] = (f32x4){b, b, b, b};
        }
#pragma unroll
        for (int ktg = 0; ktg < 15; ++ktg)
#pragma unroll
            for (int ct = 0; ct < 4; ++ct) {
                short8 bfrag = *(const short8*)(&wl[((ktg * 4 + ct) * 64 + lane) * 8]);
                acc[ct] = __builtin_amdgcn_mfma_f32_16x16x32_bf16(afr[ktg], bfrag, acc[ct], 0, 0, 0);
            }
#pragma unroll
        for (int ct = 0; ct < 4; ++ct) {
            int col = ct * 16 + (lane & 15);
#pragma unroll
            for (int j = 0; j < 4; ++j) {
                int grow = rowBase + rsub + j;
                if (grow >= N) continue;
                ZB[(size_t)grow * 64 + col] = f2b(sigmoidf_(acc[ct][j]));
            }
        }
    }
    __syncthreads();  // all reads of wl (Z weights) done
    {
        const uint4* src = (const uint4*)wfR;
        uint4* dst = (uint4*)wl;
        for (int i = t; i < 3840; i += 512) dst[i] = src[i];
    }
    __syncthreads();

    // ---- phase R ----
    {
        f32x4 acc[4];
#pragma unroll
        for (int ct = 0; ct < 4; ++ct) {
            float b = br[ct * 16 + (lane & 15)];
            acc[ct] = (f32x4){b, b, b, b};
        }
#pragma unroll
        for (int ktg = 0; ktg < 15; ++ktg)
#pragma unroll
            for (int ct = 0; ct < 4; ++ct) {
                short8 bfrag = *(const short8*)(&wl[((ktg * 4 + ct) * 64 + lane) * 8]);
                acc[ct] = __builtin_amdgcn_mfma_f32_16x16x32_bf16(afr[ktg], bfrag, acc[ct], 0, 0, 0);
            }
#pragma unroll
        for (int ct = 0; ct < 4; ++ct) {
            int col = ct * 16 + (lane & 15);
#pragma unroll
            for (int j = 0; j < 4; ++j) {
                int grow = rowBase + rsub + j;
                if (grow >= N) continue;
                // Hb from XH's bf16 H-columns (A0 = XH)
                float hb = b2f_lo((u32)A0[(size_t)grow * 96 + 32 + col]);
                HR[(size_t)grow * 64 + col] = f2b(hb * sigmoidf_(acc[ct][j]));
            }
        }
    }
}

// H~ GEMM + GRU combine: A split (X-part stride 96 from ZR buffers, H-part
// stride 64). out = Z*H + (1-Z)*tanh(acc), Z read as bf16, H f32.
__global__ __launch_bounds__(512) void gemm_h_kernel(
    const u16* __restrict__ AX0, const u16* __restrict__ AX1, const u16* __restrict__ AX2,
    const u16* __restrict__ AX3, const u16* __restrict__ AX4,
    const u16* __restrict__ AH0, const u16* __restrict__ AH1, const u16* __restrict__ AH2,
    const u16* __restrict__ AH3, const u16* __restrict__ AH4,
    const u16* __restrict__ wfrag, const float* __restrict__ bias,
    const float* __restrict__ H, const u16* __restrict__ ZB,
    float* __restrict__ Out, int N) {
    __shared__ u16 wl[30720];
    int t = threadIdx.x;
    {
        const uint4* src = (const uint4*)wfrag;
        uint4* dst = (uint4*)wl;
        for (int i = t; i < 3840; i += 512) dst[i] = src[i];
    }
    __syncthreads();

    int lane = t & 63, w = t >> 6;
    int rowBase = blockIdx.x * 128 + w * 16;
    int arow = rowBase + (lane & 15);
    int cf = (lane >> 4) * 8;

    f32x4 acc[4];
#pragma unroll
    for (int ct = 0; ct < 4; ++ct) {
        float b = bias[ct * 16 + (lane & 15)];
        acc[ct] = (f32x4){b, b, b, b};
    }

    const u16* AXs[5] = {AX0, AX1, AX2, AX3, AX4};
    const u16* AHs[5] = {AH0, AH1, AH2, AH3, AH4};
#pragma unroll
    for (int m = 0; m < 5; ++m) {
        const u16* ax = AXs[m] + (size_t)arow * 96 + cf;
        const u16* ah = AHs[m] + (size_t)arow * 64 + cf;
#pragma unroll
        for (int k3 = 0; k3 < 3; ++k3) {
            short8 a = (k3 == 0) ? *(const short8*)ax
                                 : *(const short8*)(ah + (k3 - 1) * 32);
            int ktg = m * 3 + k3;
#pragma unroll
            for (int ct = 0; ct < 4; ++ct) {
                short8 b = *(const short8*)(&wl[((ktg * 4 + ct) * 64 + lane) * 8]);
                acc[ct] = __builtin_amdgcn_mfma_f32_16x16x32_bf16(a, b, acc[ct], 0, 0, 0);
            }
        }
    }

    int rsub = (lane >> 4) * 4;
#pragma unroll
    for (int ct = 0; ct < 4; ++ct) {
        int col = ct * 16 + (lane & 15);
#pragma unroll
        for (int j = 0; j < 4; ++j) {
            int grow = rowBase + rsub + j;
            if (grow >= N) continue;
            size_t bi = (size_t)grow * 64 + col;
            float z = b2f_lo((u32)ZB[bi]);
            Out[bi] = z * H[bi] + (1.f - z) * tanhf(acc[ct][j]);
        }
    }
}

// ---------------------------------------------------------------- launch

extern "C" void kernel_launch(void* const* d_in, const int* in_sizes, int n_in,
                              void* d_out, int out_size, void* d_ws, size_t ws_size,
                              hipStream_t stream) {
    const float* X  = (const float*)d_in[0];
    const int*   ei = (const int*)d_in[1];
    const float* ew = (const float*)d_in[2];
    const float* H  = (const float*)d_in[3];
    const float* Wz = (const float*)d_in[4];
    const float* bz = (const float*)d_in[5];
    const float* Wr = (const float*)d_in[6];
    const float* br = (const float*)d_in[7];
    const float* Wh = (const float*)d_in[8];
    const float* bh = (const float*)d_in[9];
    float* out = (float*)d_out;

    const int N = in_sizes[0] / 32;   // 50000
    const int E = in_sizes[2];        // 800000
    const int NB = (N + BKT_NODES - 1) >> BKT_BITS;  // 49 (code assumes NB <= 64)

    // ---- workspace carve (256B aligned) ----
    char* wp = (char*)d_ws;
    auto alloc = [&](size_t nbytes) -> void* {
        void* p = (void*)wp;
        wp += (nbytes + 255) & ~(size_t)255;
        return p;
    };
    u16* XH   = (u16*)alloc((size_t)N * 96 * 2);   // [X|H], stays intact
    u16* T1o  = (u16*)alloc((size_t)N * 96 * 2);
    u16* T1i  = (u16*)alloc((size_t)N * 96 * 2);
    u16* U2o  = (u16*)alloc((size_t)N * 96 * 2);   // plain P*T1 (fold in W)
    u16* U2i  = (u16*)alloc((size_t)N * 96 * 2);
    u16* HR   = (u16*)alloc((size_t)N * 64 * 2);   // H*R (phase-H H-part)
    u16* T1oH = (u16*)alloc((size_t)N * 64 * 2);
    u16* T1iH = (u16*)alloc((size_t)N * 64 * 2);
    u16* U2oH = (u16*)alloc((size_t)N * 64 * 2);
    u16* U2iH = (u16*)alloc((size_t)N * 64 * 2);
    u16* ZB   = (u16*)alloc((size_t)N * 64 * 2);   // Z gate, bf16
    float* deg_in  = (float*)alloc((size_t)N * 4);
    float* deg_out = (float*)alloc((size_t)N * 4);
    int* offs_f = (int*)alloc((size_t)(N + 1) * 4);
    int* offs_b = (int*)alloc((size_t)(N + 1) * 4);
    u32* pair_f = (u32*)alloc((size_t)E * 4);
    u32* pair_b = (u32*)alloc((size_t)E * 4);
    uint2* stgF = (uint2*)alloc((size_t)NB * STG_CAP * 8);
    uint2* stgB = (uint2*)alloc((size_t)NB * STG_CAP * 8);
    u16* wf_all = (u16*)alloc((size_t)3 * 30720 * 2);
    int* gCntF  = (int*)alloc(64 * 4);
    int* gCntB  = (int*)alloc(64 * 4);
    int* bBaseF = (int*)alloc(65 * 4);
    int* bBaseB = (int*)alloc(65 * 4);
    int* flag   = (int*)alloc(256);

    const int xhBlocks = (N * 12 + NTHREADS - 1) / NTHREADS;
    const int gemmBlocks = (N + 127) / 128;
    const int binBlocks = (E + 4095) / 4096;
    const int pwBlocks = (3 * 30720 + NTHREADS - 1) / NTHREADS;
    dim3 gatherBlock(12, 32);
    const int g2NodeBlks = (N + 31) / 32;               // per direction
    const int g2Grid = ((g2NodeBlks + 3) / 4) * 8;      // dir->XCD-half swizzle
    dim3 gatherHBlock(8, 48);
    const int ghNodeBlks = (N + 47) / 48;
    const int ghGrid = ((ghNodeBlks + 3) / 4) * 8;

    // ---- edge preprocessing (bucketed CSR build) ----
    hipMemsetAsync(gCntF, 0, 64 * 4, stream);
    hipMemsetAsync(gCntB, 0, 64 * 4, stream);

    detect_i64_kernel<<<1, 256, 0, stream>>>(ei, E < 8192 ? E : 8192, flag);
    prep_weights_kernel<<<pwBlocks, NTHREADS, 0, stream>>>(Wz, Wr, Wh, wf_all);
    bin_kernel<<<binBlocks, 1024, 0, stream>>>(ei, flag, ew, gCntF, gCntB, stgF, stgB, E, NB);
    bktscan_kernel<<<1, 64, 0, stream>>>(gCntF, gCntB, bBaseF, bBaseB, offs_f, offs_b, NB, N, E);
    bktdeg_kernel<<<2 * NB, 1024, 0, stream>>>(stgF, stgB, gCntF, gCntB, deg_in, deg_out, N, NB);
    bktcsr_kernel<<<2 * NB, 1024, 0, stream>>>(stgF, stgB, gCntF, gCntB, bBaseF, bBaseB,
                                               deg_in, deg_out, offs_f, offs_b,
                                               pair_f, pair_b, N, NB);

    // ---- phase ZR: shared T matrices on XH = [X|H] (96-col gathers) ----
    build_xh_kernel<<<xhBlocks, NTHREADS, 0, stream>>>((const float4*)X, (const float4*)H,
                                                       (uint4*)XH, N);
    gather2_kernel<<<g2Grid, gatherBlock, 0, stream>>>(
        (const uint4*)XH, (const uint4*)XH, offs_f, pair_f, offs_b, pair_b,
        (uint4*)T1o, (uint4*)T1i, N);
    gather2_kernel<<<g2Grid, gatherBlock, 0, stream>>>(
        (const uint4*)T1o, (const uint4*)T1i, offs_f, pair_f, offs_b, pair_b,
        (uint4*)U2o, (uint4*)U2i, N);

    // Fused Z+R gates (A read once): Z -> ZB (bf16), HR = Hb*sigmoid (bf16)
    gemm_zr_kernel<<<gemmBlocks, 512, 0, stream>>>(
        XH, T1o, T1i, U2o, U2i, wf_all, wf_all + 30720, bz, br, ZB, HR, N);

    // ---- phase H: propagate only the 64-col H*R part (X-part reused from ZR) ----
    gather2h_kernel<<<ghGrid, gatherHBlock, 0, stream>>>(
        (const uint4*)HR, (const uint4*)HR, offs_f, pair_f, offs_b, pair_b,
        (uint4*)T1oH, (uint4*)T1iH, N);
    gather2h_kernel<<<ghGrid, gatherHBlock, 0, stream>>>(
        (const uint4*)T1oH, (const uint4*)T1iH, offs_f, pair_f, offs_b, pair_b,
        (uint4*)U2oH, (uint4*)U2iH, N);

    // H~ gate + GRU combine fused; A = [X-part from ZR buffers | H-part 64-col]
    gemm_h_kernel<<<gemmBlocks, 512, 0, stream>>>(
        XH, T1o, T1i, U2o, U2i, HR, T1oH, T1iH, U2oH, U2iH,
        wf_all + 2 * 30720, bh, H, ZB, out, N);
}

// Round 14
// 259.200 us; speedup vs baseline: 1.4417x; 1.0883x over previous
//
#include <hip/hip_runtime.h>

// DCRNN cell: 3x diffusion conv (fwd/bwd, K=3 Chebyshev) + GRU gating.
// N=50000 nodes, E=800000 edges, F_IN=32, F_OUT=64, fan=96.
// Round 14: (a) detect/bktscan folded into bin/bktdeg (kill serial-kernel
// tail); (b) CSR rows coarsely sorted by src band (src>>14, 4 bands) so
// lockstep gather waves read a ~3MB L2-resident band at a time.

#define NTHREADS 256
#define BKT_BITS 10
#define BKT_NODES 1024
#define STG_CAP 32768   // per-bucket staging capacity (expected ~16.4K)
#define BANDS 4

typedef unsigned short u16;
typedef unsigned int u32;
typedef unsigned long long u64;
typedef __attribute__((ext_vector_type(8))) short short8;   // 8 bf16 (4 VGPRs)
typedef __attribute__((ext_vector_type(4))) float f32x4;

__device__ __forceinline__ float sigmoidf_(float x) { return 1.f / (1.f + __expf(-x)); }
__device__ __forceinline__ float b2f_lo(u32 u) { return __uint_as_float(u << 16); }
__device__ __forceinline__ float b2f_hi(u32 u) { return __uint_as_float(u & 0xffff0000u); }
__device__ __forceinline__ u16 f2b(float f) {
    u32 u = __float_as_uint(f);
    return (u16)((u + 0x7fffu + ((u >> 16) & 1u)) >> 16);
}
__device__ __forceinline__ u32 pack2(float a, float b) {
    return (u32)f2b(a) | ((u32)f2b(b) << 16);
}

// ---------------------------------------------------------------- edge decode

__device__ __forceinline__ void load_edge(const int* ei, int e, int E, int i64,
                                          int& r, int& c) {
    if (i64) {
        const long long* p = (const long long*)ei;
        r = (int)p[e]; c = (int)p[E + e];
    } else {
        r = ei[e]; c = ei[E + e];
    }
}

// ---- Pass 1: bin edges into node-range buckets (both directions). ----
// Self-detects int64 vs int32 edge layout (hi-words of first 32 entries;
// index 2e+1 < 2E is in-bounds under both interpretations).
__global__ __launch_bounds__(1024) void bin_kernel(
    const int* __restrict__ ei, const float* __restrict__ ew,
    int* gCntF, int* gCntB, uint2* __restrict__ stgF, uint2* __restrict__ stgB,
    int E, int NB) {
    __shared__ int cF[64], cB[64], bF[64], bB[64];
    __shared__ int s_not64;
    int t = threadIdx.x;
    if (t == 0) s_not64 = 0;
    if (t < NB) { cF[t] = 0; cB[t] = 0; }
    __syncthreads();
    if (t < 32) { if (ei[2 * t + 1] != 0) atomicOr(&s_not64, 1); }
    __syncthreads();
    int i64 = !s_not64;
    int r[4], c[4], e[4]; float w[4];
#pragma unroll
    for (int k = 0; k < 4; ++k) {
        e[k] = blockIdx.x * 4096 + k * 1024 + t;
        if (e[k] < E) {
            load_edge(ei, e[k], E, i64, r[k], c[k]);
            w[k] = ew[e[k]];
            atomicAdd(&cF[c[k] >> BKT_BITS], 1);
            atomicAdd(&cB[r[k] >> BKT_BITS], 1);
        }
    }
    __syncthreads();
    if (t < NB) bF[t] = atomicAdd(&gCntF[t], cF[t]);
    if (t >= 256 && t < 256 + NB) bB[t - 256] = atomicAdd(&gCntB[t - 256], cB[t - 256]);
    __syncthreads();
    if (t < NB) cF[t] = 0;                      // reuse as intra-block cursor
    if (t >= 256 && t < 256 + NB) cB[t - 256] = 0;
    __syncthreads();
#pragma unroll
    for (int k = 0; k < 4; ++k) {
        if (e[k] < E) {
            int jf = c[k] >> BKT_BITS;
            int pf = bF[jf] + atomicAdd(&cF[jf], 1);
            stgF[(size_t)jf * STG_CAP + pf] =
                make_uint2(__float_as_uint(w[k]), ((u32)r[k] << BKT_BITS) | (u32)(c[k] & (BKT_NODES - 1)));
            int jb = r[k] >> BKT_BITS;
            int pb = bB[jb] + atomicAdd(&cB[jb], 1);
            stgB[(size_t)jb * STG_CAP + pb] =
                make_uint2(__float_as_uint(w[k]), ((u32)c[k] << BKT_BITS) | (u32)(r[k] & (BKT_NODES - 1)));
        }
    }
}

// ---- Pass 2a: weighted degrees per bucket (LDS); block 2*NB does the
// bucket-total scans (old bktscan). ----
__global__ __launch_bounds__(1024) void bktdeg_kernel(
    const uint2* __restrict__ stgF, const uint2* __restrict__ stgB,
    const int* __restrict__ gCntF, const int* __restrict__ gCntB,
    float* __restrict__ deg_in, float* __restrict__ deg_out,
    int* bBaseF, int* bBaseB, int* of, int* ob,
    int N, int NB, int E) {
    int j = blockIdx.x, t = threadIdx.x;
    if (j == 2 * NB) {   // scan block
        if (t == 0) {
            int s = 0;
            for (int q = 0; q < NB; ++q) { bBaseF[q] = s; s += gCntF[q]; }
            bBaseF[NB] = s; of[N] = E;
        }
        if (t == 1) {
            int s = 0;
            for (int q = 0; q < NB; ++q) { bBaseB[q] = s; s += gCntB[q]; }
            bBaseB[NB] = s; ob[N] = E;
        }
        return;
    }
    __shared__ float acc[BKT_NODES];
    bool fwd = j < NB;
    int jb = fwd ? j : j - NB;
    acc[t] = 0.f;
    __syncthreads();
    const uint2* stg = (fwd ? stgF : stgB) + (size_t)jb * STG_CAP;
    int m = fwd ? gCntF[jb] : gCntB[jb];
    for (int i = t; i < m; i += 1024) {
        uint2 p = stg[i];
        atomicAdd(&acc[p.y & (BKT_NODES - 1)], __uint_as_float(p.x));
    }
    __syncthreads();
    int n = jb * BKT_NODES + t;
    if (n < N) { if (fwd) deg_in[n] = acc[t]; else deg_out[n] = acc[t]; }
}

// ---- Pass 2b: per-node offs + CSR payload, rows grouped by src band. ----
__global__ __launch_bounds__(1024) void bktcsr_kernel(
    const uint2* __restrict__ stgF, const uint2* __restrict__ stgB,
    const int* __restrict__ gCntF, const int* __restrict__ gCntB,
    const int* __restrict__ bBaseF, const int* __restrict__ bBaseB,
    const float* __restrict__ deg_in, const float* __restrict__ deg_out,
    int* __restrict__ of, int* __restrict__ ob,
    u32* __restrict__ pf, u32* __restrict__ pb, int N, int NB) {
    __shared__ int cnt[BKT_NODES * BANDS];   // counts, then cursors (16 KB)
    __shared__ int scn[1024];
    int j = blockIdx.x, t = threadIdx.x;
    bool fwd = j < NB;
    int jb = fwd ? j : j - NB;
    const uint2* stg = (fwd ? stgF : stgB) + (size_t)jb * STG_CAP;
    int m = fwd ? gCntF[jb] : gCntB[jb];
    int base = fwd ? bBaseF[jb] : bBaseB[jb];
    const float* degS = fwd ? deg_out : deg_in;  // coeff divides by SRC-side degree
#pragma unroll
    for (int b = 0; b < BANDS; ++b) cnt[t * BANDS + b] = 0;
    __syncthreads();
    for (int i = t; i < m; i += 1024) {
        uint2 p = stg[i];
        int dl = p.y & (BKT_NODES - 1);
        int src = p.y >> BKT_BITS;
        atomicAdd(&cnt[dl * BANDS + (src >> 14)], 1);
    }
    __syncthreads();
    int c0 = cnt[t * BANDS], c1 = cnt[t * BANDS + 1];
    int c2 = cnt[t * BANDS + 2], c3 = cnt[t * BANDS + 3];
    int rowsum = c0 + c1 + c2 + c3;
    scn[t] = rowsum;
    __syncthreads();
    for (int d = 1; d < 1024; d <<= 1) {
        int x = (t >= d) ? scn[t - d] : 0;
        __syncthreads();
        scn[t] += x;
        __syncthreads();
    }
    int rowbase = scn[t] - rowsum;  // exclusive
    int n = jb * BKT_NODES + t;
    if (n < N) { if (fwd) of[n] = base + rowbase; else ob[n] = base + rowbase; }
    __syncthreads();
    cnt[t * BANDS + 0] = rowbase;
    cnt[t * BANDS + 1] = rowbase + c0;
    cnt[t * BANDS + 2] = rowbase + c0 + c1;
    cnt[t * BANDS + 3] = rowbase + c0 + c1 + c2;
    __syncthreads();
    for (int i = t; i < m; i += 1024) {
        uint2 p = stg[i];
        int dl = p.y & (BKT_NODES - 1);
        int src = p.y >> BKT_BITS;
        float coeff = __uint_as_float(p.x) / degS[src];
        int pos = base + atomicAdd(&cnt[dl * BANDS + (src >> 14)], 1);
        u32 packed = ((u32)src << 16) | (u32)f2b(coeff);  // assumes src < 65536
        if (fwd) pf[pos] = packed; else pb[pos] = packed;
    }
}

// XH = [X | H] in bf16. Each thread emits 8 bf16 (16B). N*12 chunks.
__global__ void build_xh_kernel(const float4* __restrict__ X4, const float4* __restrict__ H4,
                                uint4* __restrict__ XH, int N) {
    int idx = blockIdx.x * blockDim.x + threadIdx.x;
    if (idx >= N * 12) return;
    int n = idx / 12, c = idx % 12;
    float4 a, b;
    if (c < 4) { a = X4[n * 8 + c * 2]; b = X4[n * 8 + c * 2 + 1]; }
    else       { a = H4[n * 16 + (c - 4) * 2]; b = H4[n * 16 + (c - 4) * 2 + 1]; }
    uint4 o;
    o.x = pack2(a.x, a.y); o.y = pack2(a.z, a.w);
    o.z = pack2(b.x, b.y); o.w = pack2(b.z, b.w);
    XH[idx] = o;
}

#define GACC(vv, ww) \
    a0 += (ww) * b2f_lo((vv).x); a1 += (ww) * b2f_hi((vv).x); \
    a2 += (ww) * b2f_lo((vv).y); a3 += (ww) * b2f_hi((vv).y); \
    a4 += (ww) * b2f_lo((vv).z); a5 += (ww) * b2f_hi((vv).z); \
    a6 += (ww) * b2f_lo((vv).w); a7 += (ww) * b2f_hi((vv).w);

// Dual-direction bf16 gather, 96-col rows. blockDim = (12, 32). Unroll x4.
// direction->XCD-half swizzle: r = bid & 7; dir = r >= 4.
__global__ __launch_bounds__(384) void gather2_kernel(
    const uint4* __restrict__ xf, const uint4* __restrict__ xb,
    const int* __restrict__ offs_f, const u32* __restrict__ pf,
    const int* __restrict__ offs_b, const u32* __restrict__ pb,
    uint4* __restrict__ outf, uint4* __restrict__ outb, int N) {
    int bid = blockIdx.x;
    int rb = bid & 7;
    int dir = rb >> 2;
    int nblk = (bid >> 3) * 4 + (rb & 3);
    int n = nblk * 32 + threadIdx.y;
    if (n >= N) return;
    const uint4* x; const int* offs; const u32* pr; uint4* out;
    if (dir == 0) { x = xf; offs = offs_f; pr = pf; out = outf; }
    else          { x = xb; offs = offs_b; pr = pb; out = outb; }
    int c = threadIdx.x;  // 0..11
    int s0 = offs[n], s1 = offs[n + 1];
    float a0 = 0, a1 = 0, a2 = 0, a3 = 0, a4 = 0, a5 = 0, a6 = 0, a7 = 0;
    int o = s0;
    for (; o + 4 <= s1; o += 4) {
        u32 p0 = pr[o], p1 = pr[o + 1], p2 = pr[o + 2], p3 = pr[o + 3];
        uint4 v0 = x[(size_t)(p0 >> 16) * 12 + c];
        uint4 v1 = x[(size_t)(p1 >> 16) * 12 + c];
        uint4 v2 = x[(size_t)(p2 >> 16) * 12 + c];
        uint4 v3 = x[(size_t)(p3 >> 16) * 12 + c];
        float w0 = b2f_lo(p0), w1 = b2f_lo(p1), w2 = b2f_lo(p2), w3 = b2f_lo(p3);
        GACC(v0, w0) GACC(v1, w1) GACC(v2, w2) GACC(v3, w3)
    }
    for (; o < s1; ++o) {
        u32 p0 = pr[o];
        uint4 v0 = x[(size_t)(p0 >> 16) * 12 + c];
        float w0 = b2f_lo(p0);
        GACC(v0, w0)
    }
    size_t oi = (size_t)n * 12 + c;
    uint4 ov;
    ov.x = pack2(a0, a1); ov.y = pack2(a2, a3);
    ov.z = pack2(a4, a5); ov.w = pack2(a6, a7);
    out[oi] = ov;
}

// Dual-direction bf16 gather, 64-col rows (phase-H H-part). blockDim = (8, 48).
__global__ __launch_bounds__(384) void gather2h_kernel(
    const uint4* __restrict__ xf, const uint4* __restrict__ xb,
    const int* __restrict__ offs_f, const u32* __restrict__ pf,
    const int* __restrict__ offs_b, const u32* __restrict__ pb,
    uint4* __restrict__ outf, uint4* __restrict__ outb, int N) {
    int bid = blockIdx.x;
    int rb = bid & 7;
    int dir = rb >> 2;
    int nblk = (bid >> 3) * 4 + (rb & 3);
    int n = nblk * 48 + threadIdx.y;
    if (n >= N) return;
    const uint4* x; const int* offs; const u32* pr; uint4* out;
    if (dir == 0) { x = xf; offs = offs_f; pr = pf; out = outf; }
    else          { x = xb; offs = offs_b; pr = pb; out = outb; }
    int c = threadIdx.x;  // 0..7
    int s0 = offs[n], s1 = offs[n + 1];
    float a0 = 0, a1 = 0, a2 = 0, a3 = 0, a4 = 0, a5 = 0, a6 = 0, a7 = 0;
    int o = s0;
    for (; o + 4 <= s1; o += 4) {
        u32 p0 = pr[o], p1 = pr[o + 1], p2 = pr[o + 2], p3 = pr[o + 3];
        uint4 v0 = x[(size_t)(p0 >> 16) * 8 + c];
        uint4 v1 = x[(size_t)(p1 >> 16) * 8 + c];
        uint4 v2 = x[(size_t)(p2 >> 16) * 8 + c];
        uint4 v3 = x[(size_t)(p3 >> 16) * 8 + c];
        float w0 = b2f_lo(p0), w1 = b2f_lo(p1), w2 = b2f_lo(p2), w3 = b2f_lo(p3);
        GACC(v0, w0) GACC(v1, w1) GACC(v2, w2) GACC(v3, w3)
    }
    for (; o < s1; ++o) {
        u32 p0 = pr[o];
        uint4 v0 = x[(size_t)(p0 >> 16) * 8 + c];
        float w0 = b2f_lo(p0);
        GACC(v0, w0)
    }
    size_t oi = (size_t)n * 8 + c;
    uint4 ov;
    ov.x = pack2(a0, a1); ov.y = pack2(a2, a3);
    ov.z = pack2(a4, a5); ov.w = pack2(a6, a7);
    out[oi] = ov;
}

// Fuse + swizzle gate weights into MFMA-fragment-linear bf16, with the
// Chebyshev fold: seg0 = W00+W10-W02-W12, seg1 = W01, seg2 = W11,
// seg3 = 2*W02, seg4 = 2*W12. One thread per element.
__global__ void prep_weights_kernel(const float* __restrict__ Wz, const float* __restrict__ Wr,
                                    const float* __restrict__ Wh, u16* __restrict__ wf_all) {
    const int KS = 96 * 64;
    int idx = blockIdx.x * blockDim.x + threadIdx.x;
    if (idx >= 3 * 30720) return;
    int g = idx / 30720, i = idx - g * 30720;
    const float* W = (g == 0) ? Wz : (g == 1) ? Wr : Wh;
    int j = i & 7, lane = (i >> 3) & 63, ct = (i >> 9) & 3, kt = i >> 11;
    int k = kt * 32 + (lane >> 4) * 8 + j;
    int col = ct * 16 + (lane & 15);
    int m = k / 96, fr = k - m * 96;
    int e = fr * 64 + col;
    float v;
    if (m == 0)      v = W[e] + W[3 * KS + e] - W[2 * KS + e] - W[5 * KS + e];
    else if (m == 1) v = W[1 * KS + e];
    else if (m == 2) v = W[4 * KS + e];
    else if (m == 3) v = 2.f * W[2 * KS + e];
    else             v = 2.f * W[5 * KS + e];
    wf_all[idx] = f2b(v);
}

// Fused Z+R GEMM: A (5 matrices, [N,96]) read ONCE into registers; two-phase
// LDS weight staging. Writes Z (bf16) and HR = Hb*sigmoid(accR) (bf16).
__global__ __launch_bounds__(512) void gemm_zr_kernel(
    const u16* __restrict__ A0, const u16* __restrict__ A1, const u16* __restrict__ A2,
    const u16* __restrict__ A3, const u16* __restrict__ A4,
    const u16* __restrict__ wfZ, const u16* __restrict__ wfR,
    const float* __restrict__ bz, const float* __restrict__ br,
    u16* __restrict__ ZB, u16* __restrict__ HR, int N) {
    __shared__ u16 wl[30720];  // 61440 B -> 2 blocks/CU
    int t = threadIdx.x;
    {
        const uint4* src = (const uint4*)wfZ;
        uint4* dst = (uint4*)wl;
        for (int i = t; i < 3840; i += 512) dst[i] = src[i];
    }

    int lane = t & 63, w = t >> 6;
    int rowBase = blockIdx.x * 128 + w * 16;
    int arow = rowBase + (lane & 15);
    int cf = (lane >> 4) * 8;
    int rsub = (lane >> 4) * 4;

    // Load all 15 A fragments (held across both phases).
    short8 afr[15];
    const u16* As[5] = {A0, A1, A2, A3, A4};
#pragma unroll
    for (int m = 0; m < 5; ++m) {
        const u16* a = As[m] + (size_t)arow * 96 + cf;
        afr[m * 3 + 0] = *(const short8*)(a);
        afr[m * 3 + 1] = *(const short8*)(a + 32);
        afr[m * 3 + 2] = *(const short8*)(a + 64);
    }
    __syncthreads();

    // ---- phase Z ----
    {
        f32x4 acc[4];
#pragma unroll
        for (int ct = 0; ct < 4; ++ct) {
            float b = bz[ct * 16 + (lane & 15)];
            acc[ct] = (f32x4){b, b, b, b};
        }
#pragma unroll
        for (int ktg = 0; ktg < 15; ++ktg)
#pragma unroll
            for (int ct = 0; ct < 4; ++ct) {
                short8 bfrag = *(const short8*)(&wl[((ktg * 4 + ct) * 64 + lane) * 8]);
                acc[ct] = __builtin_amdgcn_mfma_f32_16x16x32_bf16(afr[ktg], bfrag, acc[ct], 0, 0, 0);
            }
#pragma unroll
        for (int ct = 0; ct < 4; ++ct) {
            int col = ct * 16 + (lane & 15);
#pragma unroll
            for (int j = 0; j < 4; ++j) {
                int grow = rowBase + rsub + j;
                if (grow >= N) continue;
                ZB[(size_t)grow * 64 + col] = f2b(sigmoidf_(acc[ct][j]));
            }
        }
    }
    __syncthreads();  // all reads of wl (Z weights) done
    {
        const uint4* src = (const uint4*)wfR;
        uint4* dst = (uint4*)wl;
        for (int i = t; i < 3840; i += 512) dst[i] = src[i];
    }
    __syncthreads();

    // ---- phase R ----
    {
        f32x4 acc[4];
#pragma unroll
        for (int ct = 0; ct < 4; ++ct) {
            float b = br[ct * 16 + (lane & 15)];
            acc[ct] = (f32x4){b, b, b, b};
        }
#pragma unroll
        for (int ktg = 0; ktg < 15; ++ktg)
#pragma unroll
            for (int ct = 0; ct < 4; ++ct) {
                short8 bfrag = *(const short8*)(&wl[((ktg * 4 + ct) * 64 + lane) * 8]);
                acc[ct] = __builtin_amdgcn_mfma_f32_16x16x32_bf16(afr[ktg], bfrag, acc[ct], 0, 0, 0);
            }
#pragma unroll
        for (int ct = 0; ct < 4; ++ct) {
            int col = ct * 16 + (lane & 15);
#pragma unroll
            for (int j = 0; j < 4; ++j) {
                int grow = rowBase + rsub + j;
                if (grow >= N) continue;
                // Hb from XH's bf16 H-columns (A0 = XH)
                float hb = b2f_lo((u32)A0[(size_t)grow * 96 + 32 + col]);
                HR[(size_t)grow * 64 + col] = f2b(hb * sigmoidf_(acc[ct][j]));
            }
        }
    }
}

// H~ GEMM + GRU combine: A split (X-part stride 96 from ZR buffers, H-part
// stride 64). out = Z*H + (1-Z)*tanh(acc), Z read as bf16, H f32.
__global__ __launch_bounds__(512) void gemm_h_kernel(
    const u16* __restrict__ AX0, const u16* __restrict__ AX1, const u16* __restrict__ AX2,
    const u16* __restrict__ AX3, const u16* __restrict__ AX4,
    const u16* __restrict__ AH0, const u16* __restrict__ AH1, const u16* __restrict__ AH2,
    const u16* __restrict__ AH3, const u16* __restrict__ AH4,
    const u16* __restrict__ wfrag, const float* __restrict__ bias,
    const float* __restrict__ H, const u16* __restrict__ ZB,
    float* __restrict__ Out, int N) {
    __shared__ u16 wl[30720];
    int t = threadIdx.x;
    {
        const uint4* src = (const uint4*)wfrag;
        uint4* dst = (uint4*)wl;
        for (int i = t; i < 3840; i += 512) dst[i] = src[i];
    }
    __syncthreads();

    int lane = t & 63, w = t >> 6;
    int rowBase = blockIdx.x * 128 + w * 16;
    int arow = rowBase + (lane & 15);
    int cf = (lane >> 4) * 8;

    f32x4 acc[4];
#pragma unroll
    for (int ct = 0; ct < 4; ++ct) {
        float b = bias[ct * 16 + (lane & 15)];
        acc[ct] = (f32x4){b, b, b, b};
    }

    const u16* AXs[5] = {AX0, AX1, AX2, AX3, AX4};
    const u16* AHs[5] = {AH0, AH1, AH2, AH3, AH4};
#pragma unroll
    for (int m = 0; m < 5; ++m) {
        const u16* ax = AXs[m] + (size_t)arow * 96 + cf;
        const u16* ah = AHs[m] + (size_t)arow * 64 + cf;
#pragma unroll
        for (int k3 = 0; k3 < 3; ++k3) {
            short8 a = (k3 == 0) ? *(const short8*)ax
                                 : *(const short8*)(ah + (k3 - 1) * 32);
            int ktg = m * 3 + k3;
#pragma unroll
            for (int ct = 0; ct < 4; ++ct) {
                short8 b = *(const short8*)(&wl[((ktg * 4 + ct) * 64 + lane) * 8]);
                acc[ct] = __builtin_amdgcn_mfma_f32_16x16x32_bf16(a, b, acc[ct], 0, 0, 0);
            }
        }
    }

    int rsub = (lane >> 4) * 4;
#pragma unroll
    for (int ct = 0; ct < 4; ++ct) {
        int col = ct * 16 + (lane & 15);
#pragma unroll
        for (int j = 0; j < 4; ++j) {
            int grow = rowBase + rsub + j;
            if (grow >= N) continue;
            size_t bi = (size_t)grow * 64 + col;
            float z = b2f_lo((u32)ZB[bi]);
            Out[bi] = z * H[bi] + (1.f - z) * tanhf(acc[ct][j]);
        }
    }
}

// ---------------------------------------------------------------- launch

extern "C" void kernel_launch(void* const* d_in, const int* in_sizes, int n_in,
                              void* d_out, int out_size, void* d_ws, size_t ws_size,
                              hipStream_t stream) {
    const float* X  = (const float*)d_in[0];
    const int*   ei = (const int*)d_in[1];
    const float* ew = (const float*)d_in[2];
    const float* H  = (const float*)d_in[3];
    const float* Wz = (const float*)d_in[4];
    const float* bz = (const float*)d_in[5];
    const float* Wr = (const float*)d_in[6];
    const float* br = (const float*)d_in[7];
    const float* Wh = (const float*)d_in[8];
    const float* bh = (const float*)d_in[9];
    float* out = (float*)d_out;

    const int N = in_sizes[0] / 32;   // 50000
    const int E = in_sizes[2];        // 800000
    const int NB = (N + BKT_NODES - 1) >> BKT_BITS;  // 49 (code assumes NB <= 64)

    // ---- workspace carve (256B aligned) ----
    char* wp = (char*)d_ws;
    auto alloc = [&](size_t nbytes) -> void* {
        void* p = (void*)wp;
        wp += (nbytes + 255) & ~(size_t)255;
        return p;
    };
    u16* XH   = (u16*)alloc((size_t)N * 96 * 2);   // [X|H], stays intact
    u16* T1o  = (u16*)alloc((size_t)N * 96 * 2);
    u16* T1i  = (u16*)alloc((size_t)N * 96 * 2);
    u16* U2o  = (u16*)alloc((size_t)N * 96 * 2);   // plain P*T1 (fold in W)
    u16* U2i  = (u16*)alloc((size_t)N * 96 * 2);
    u16* HR   = (u16*)alloc((size_t)N * 64 * 2);   // H*R (phase-H H-part)
    u16* T1oH = (u16*)alloc((size_t)N * 64 * 2);
    u16* T1iH = (u16*)alloc((size_t)N * 64 * 2);
    u16* U2oH = (u16*)alloc((size_t)N * 64 * 2);
    u16* U2iH = (u16*)alloc((size_t)N * 64 * 2);
    u16* ZB   = (u16*)alloc((size_t)N * 64 * 2);   // Z gate, bf16
    float* deg_in  = (float*)alloc((size_t)N * 4);
    float* deg_out = (float*)alloc((size_t)N * 4);
    int* offs_f = (int*)alloc((size_t)(N + 1) * 4);
    int* offs_b = (int*)alloc((size_t)(N + 1) * 4);
    u32* pair_f = (u32*)alloc((size_t)E * 4);
    u32* pair_b = (u32*)alloc((size_t)E * 4);
    uint2* stgF = (uint2*)alloc((size_t)NB * STG_CAP * 8);
    uint2* stgB = (uint2*)alloc((size_t)NB * STG_CAP * 8);
    u16* wf_all = (u16*)alloc((size_t)3 * 30720 * 2);
    int* gCntF  = (int*)alloc(64 * 4);
    int* gCntB  = (int*)alloc(64 * 4);
    int* bBaseF = (int*)alloc(65 * 4);
    int* bBaseB = (int*)alloc(65 * 4);

    const int xhBlocks = (N * 12 + NTHREADS - 1) / NTHREADS;
    const int gemmBlocks = (N + 127) / 128;
    const int binBlocks = (E + 4095) / 4096;
    const int pwBlocks = (3 * 30720 + NTHREADS - 1) / NTHREADS;
    dim3 gatherBlock(12, 32);
    const int g2NodeBlks = (N + 31) / 32;               // per direction
    const int g2Grid = ((g2NodeBlks + 3) / 4) * 8;      // dir->XCD-half swizzle
    dim3 gatherHBlock(8, 48);
    const int ghNodeBlks = (N + 47) / 48;
    const int ghGrid = ((ghNodeBlks + 3) / 4) * 8;

    // ---- edge preprocessing (bucketed CSR build) ----
    hipMemsetAsync(gCntF, 0, 64 * 4, stream);
    hipMemsetAsync(gCntB, 0, 64 * 4, stream);

    prep_weights_kernel<<<pwBlocks, NTHREADS, 0, stream>>>(Wz, Wr, Wh, wf_all);
    bin_kernel<<<binBlocks, 1024, 0, stream>>>(ei, ew, gCntF, gCntB, stgF, stgB, E, NB);
    bktdeg_kernel<<<2 * NB + 1, 1024, 0, stream>>>(stgF, stgB, gCntF, gCntB,
                                                   deg_in, deg_out,
                                                   bBaseF, bBaseB, offs_f, offs_b,
                                                   N, NB, E);
    bktcsr_kernel<<<2 * NB, 1024, 0, stream>>>(stgF, stgB, gCntF, gCntB, bBaseF, bBaseB,
                                               deg_in, deg_out, offs_f, offs_b,
                                               pair_f, pair_b, N, NB);

    // ---- phase ZR: shared T matrices on XH = [X|H] (96-col gathers) ----
    build_xh_kernel<<<xhBlocks, NTHREADS, 0, stream>>>((const float4*)X, (const float4*)H,
                                                       (uint4*)XH, N);
    gather2_kernel<<<g2Grid, gatherBlock, 0, stream>>>(
        (const uint4*)XH, (const uint4*)XH, offs_f, pair_f, offs_b, pair_b,
        (uint4*)T1o, (uint4*)T1i, N);
    gather2_kernel<<<g2Grid, gatherBlock, 0, stream>>>(
        (const uint4*)T1o, (const uint4*)T1i, offs_f, pair_f, offs_b, pair_b,
        (uint4*)U2o, (uint4*)U2i, N);

    // Fused Z+R gates (A read once): Z -> ZB (bf16), HR = Hb*sigmoid (bf16)
    gemm_zr_kernel<<<gemmBlocks, 512, 0, stream>>>(
        XH, T1o, T1i, U2o, U2i, wf_all, wf_all + 30720, bz, br, ZB, HR, N);

    // ---- phase H: propagate only the 64-col H*R part (X-part reused from ZR) ----
    gather2h_kernel<<<ghGrid, gatherHBlock, 0, stream>>>(
        (const uint4*)HR, (const uint4*)HR, offs_f, pair_f, offs_b, pair_b,
        (uint4*)T1oH, (uint4*)T1iH, N);
    gather2h_kernel<<<ghGrid, gatherHBlock, 0, stream>>>(
        (const uint4*)T1oH, (const uint4*)T1iH, offs_f, pair_f, offs_b, pair_b,
        (uint4*)U2oH, (uint4*)U2iH, N);

    // H~ gate + GRU combine fused; A = [X-part from ZR buffers | H-part 64-col]
    gemm_h_kernel<<<gemmBlocks, 512, 0, stream>>>(
        XH, T1o, T1i, U2o, U2i, HR, T1oH, T1iH, U2oH, U2iH,
        wf_all + 2 * 30720, bh, H, ZB, out, N);
}

// Round 15
// 258.762 us; speedup vs baseline: 1.4441x; 1.0017x over previous
//
#include <hip/hip_runtime.h>

// DCRNN cell: 3x diffusion conv (fwd/bwd, K=3 Chebyshev) + GRU gating.
// N=50000 nodes, E=800000 edges, F_IN=32, F_OUT=64, fan=96.
// Round 15: BANDS 4->8 (src>>13; 1.55MB band working set per XCD) and
// count-pass fusion: bktdeg emits per-(row,band) counts so bktcsr skips
// its own counting read of the 25.6MB staging array.

#define NTHREADS 256
#define BKT_BITS 10
#define BKT_NODES 1024
#define STG_CAP 32768   // per-bucket staging capacity (expected ~16.4K)
#define BANDS 8
#define BAND_SHIFT 13

typedef unsigned short u16;
typedef unsigned int u32;
typedef unsigned long long u64;
typedef __attribute__((ext_vector_type(8))) short short8;   // 8 bf16 (4 VGPRs)
typedef __attribute__((ext_vector_type(4))) float f32x4;

__device__ __forceinline__ float sigmoidf_(float x) { return 1.f / (1.f + __expf(-x)); }
__device__ __forceinline__ float b2f_lo(u32 u) { return __uint_as_float(u << 16); }
__device__ __forceinline__ float b2f_hi(u32 u) { return __uint_as_float(u & 0xffff0000u); }
__device__ __forceinline__ u16 f2b(float f) {
    u32 u = __float_as_uint(f);
    return (u16)((u + 0x7fffu + ((u >> 16) & 1u)) >> 16);
}
__device__ __forceinline__ u32 pack2(float a, float b) {
    return (u32)f2b(a) | ((u32)f2b(b) << 16);
}

// ---------------------------------------------------------------- edge decode

__device__ __forceinline__ void load_edge(const int* ei, int e, int E, int i64,
                                          int& r, int& c) {
    if (i64) {
        const long long* p = (const long long*)ei;
        r = (int)p[e]; c = (int)p[E + e];
    } else {
        r = ei[e]; c = ei[E + e];
    }
}

// ---- Pass 1: bin edges into node-range buckets (both directions). ----
// Self-detects int64 vs int32 edge layout (hi-words of first 32 entries).
__global__ __launch_bounds__(1024) void bin_kernel(
    const int* __restrict__ ei, const float* __restrict__ ew,
    int* gCntF, int* gCntB, uint2* __restrict__ stgF, uint2* __restrict__ stgB,
    int E, int NB) {
    __shared__ int cF[64], cB[64], bF[64], bB[64];
    __shared__ int s_not64;
    int t = threadIdx.x;
    if (t == 0) s_not64 = 0;
    if (t < NB) { cF[t] = 0; cB[t] = 0; }
    __syncthreads();
    if (t < 32) { if (ei[2 * t + 1] != 0) atomicOr(&s_not64, 1); }
    __syncthreads();
    int i64 = !s_not64;
    int r[4], c[4], e[4]; float w[4];
#pragma unroll
    for (int k = 0; k < 4; ++k) {
        e[k] = blockIdx.x * 4096 + k * 1024 + t;
        if (e[k] < E) {
            load_edge(ei, e[k], E, i64, r[k], c[k]);
            w[k] = ew[e[k]];
            atomicAdd(&cF[c[k] >> BKT_BITS], 1);
            atomicAdd(&cB[r[k] >> BKT_BITS], 1);
        }
    }
    __syncthreads();
    if (t < NB) bF[t] = atomicAdd(&gCntF[t], cF[t]);
    if (t >= 256 && t < 256 + NB) bB[t - 256] = atomicAdd(&gCntB[t - 256], cB[t - 256]);
    __syncthreads();
    if (t < NB) cF[t] = 0;                      // reuse as intra-block cursor
    if (t >= 256 && t < 256 + NB) cB[t - 256] = 0;
    __syncthreads();
#pragma unroll
    for (int k = 0; k < 4; ++k) {
        if (e[k] < E) {
            int jf = c[k] >> BKT_BITS;
            int pf = bF[jf] + atomicAdd(&cF[jf], 1);
            stgF[(size_t)jf * STG_CAP + pf] =
                make_uint2(__float_as_uint(w[k]), ((u32)r[k] << BKT_BITS) | (u32)(c[k] & (BKT_NODES - 1)));
            int jb = r[k] >> BKT_BITS;
            int pb = bB[jb] + atomicAdd(&cB[jb], 1);
            stgB[(size_t)jb * STG_CAP + pb] =
                make_uint2(__float_as_uint(w[k]), ((u32)c[k] << BKT_BITS) | (u32)(r[k] & (BKT_NODES - 1)));
        }
    }
}

// ---- Pass 2a: weighted degrees + per-(row,band) counts per bucket.
// Block 2*NB does the bucket-total scans. ----
__global__ __launch_bounds__(1024) void bktdeg_kernel(
    const uint2* __restrict__ stgF, const uint2* __restrict__ stgB,
    const int* __restrict__ gCntF, const int* __restrict__ gCntB,
    float* __restrict__ deg_in, float* __restrict__ deg_out,
    int* __restrict__ cntG,
    int* bBaseF, int* bBaseB, int* of, int* ob,
    int N, int NB, int E) {
    int j = blockIdx.x, t = threadIdx.x;
    if (j == 2 * NB) {   // scan block
        if (t == 0) {
            int s = 0;
            for (int q = 0; q < NB; ++q) { bBaseF[q] = s; s += gCntF[q]; }
            bBaseF[NB] = s; of[N] = E;
        }
        if (t == 1) {
            int s = 0;
            for (int q = 0; q < NB; ++q) { bBaseB[q] = s; s += gCntB[q]; }
            bBaseB[NB] = s; ob[N] = E;
        }
        return;
    }
    __shared__ float acc[BKT_NODES];
    __shared__ int cnt[BKT_NODES * BANDS];   // 32 KB
    bool fwd = j < NB;
    int jb = fwd ? j : j - NB;
    acc[t] = 0.f;
#pragma unroll
    for (int b = 0; b < BANDS; ++b) cnt[t * BANDS + b] = 0;
    __syncthreads();
    const uint2* stg = (fwd ? stgF : stgB) + (size_t)jb * STG_CAP;
    int m = fwd ? gCntF[jb] : gCntB[jb];
    for (int i = t; i < m; i += 1024) {
        uint2 p = stg[i];
        int dl = p.y & (BKT_NODES - 1);
        int src = p.y >> BKT_BITS;
        atomicAdd(&acc[dl], __uint_as_float(p.x));
        atomicAdd(&cnt[dl * BANDS + (src >> BAND_SHIFT)], 1);
    }
    __syncthreads();
    int n = jb * BKT_NODES + t;
    if (n < N) { if (fwd) deg_in[n] = acc[t]; else deg_out[n] = acc[t]; }
    // dump counts coalesced (8192 ints = 2048 int4)
    int4* cg = (int4*)(cntG + (size_t)j * (BKT_NODES * BANDS));
    const int4* cl = (const int4*)cnt;
    for (int i = t; i < BKT_NODES * BANDS / 4; i += 1024) cg[i] = cl[i];
}

// ---- Pass 2b: per-node offs + CSR payload, rows grouped by src band.
// Counts come from cntG (no re-read of stg for counting). ----
__global__ __launch_bounds__(1024) void bktcsr_kernel(
    const uint2* __restrict__ stgF, const uint2* __restrict__ stgB,
    const int* __restrict__ gCntF, const int* __restrict__ gCntB,
    const int* __restrict__ bBaseF, const int* __restrict__ bBaseB,
    const int* __restrict__ cntG,
    const float* __restrict__ deg_in, const float* __restrict__ deg_out,
    int* __restrict__ of, int* __restrict__ ob,
    u32* __restrict__ pf, u32* __restrict__ pb, int N, int NB) {
    __shared__ int cnt[BKT_NODES * BANDS];   // cursors (32 KB)
    __shared__ int scn[1024];
    int j = blockIdx.x, t = threadIdx.x;
    bool fwd = j < NB;
    int jb = fwd ? j : j - NB;
    const uint2* stg = (fwd ? stgF : stgB) + (size_t)jb * STG_CAP;
    int m = fwd ? gCntF[jb] : gCntB[jb];
    int base = fwd ? bBaseF[jb] : bBaseB[jb];
    const float* degS = fwd ? deg_out : deg_in;  // coeff divides by SRC-side degree
    {
        int4* cl = (int4*)cnt;
        const int4* cg = (const int4*)(cntG + (size_t)j * (BKT_NODES * BANDS));
        for (int i = t; i < BKT_NODES * BANDS / 4; i += 1024) cl[i] = cg[i];
    }
    __syncthreads();
    int c[BANDS]; int rowsum = 0;
#pragma unroll
    for (int b = 0; b < BANDS; ++b) { c[b] = cnt[t * BANDS + b]; rowsum += c[b]; }
    scn[t] = rowsum;
    __syncthreads();
    for (int d = 1; d < 1024; d <<= 1) {
        int x = (t >= d) ? scn[t - d] : 0;
        __syncthreads();
        scn[t] += x;
        __syncthreads();
    }
    int rowbase = scn[t] - rowsum;  // exclusive
    int n = jb * BKT_NODES + t;
    if (n < N) { if (fwd) of[n] = base + rowbase; else ob[n] = base + rowbase; }
    __syncthreads();
    int run = rowbase;
#pragma unroll
    for (int b = 0; b < BANDS; ++b) { cnt[t * BANDS + b] = run; run += c[b]; }
    __syncthreads();
    for (int i = t; i < m; i += 1024) {
        uint2 p = stg[i];
        int dl = p.y & (BKT_NODES - 1);
        int src = p.y >> BKT_BITS;
        float coeff = __uint_as_float(p.x) / degS[src];
        int pos = base + atomicAdd(&cnt[dl * BANDS + (src >> BAND_SHIFT)], 1);
        u32 packed = ((u32)src << 16) | (u32)f2b(coeff);  // assumes src < 65536
        if (fwd) pf[pos] = packed; else pb[pos] = packed;
    }
}

// XH = [X | H] in bf16. Each thread emits 8 bf16 (16B). N*12 chunks.
__global__ void build_xh_kernel(const float4* __restrict__ X4, const float4* __restrict__ H4,
                                uint4* __restrict__ XH, int N) {
    int idx = blockIdx.x * blockDim.x + threadIdx.x;
    if (idx >= N * 12) return;
    int n = idx / 12, c = idx % 12;
    float4 a, b;
    if (c < 4) { a = X4[n * 8 + c * 2]; b = X4[n * 8 + c * 2 + 1]; }
    else       { a = H4[n * 16 + (c - 4) * 2]; b = H4[n * 16 + (c - 4) * 2 + 1]; }
    uint4 o;
    o.x = pack2(a.x, a.y); o.y = pack2(a.z, a.w);
    o.z = pack2(b.x, b.y); o.w = pack2(b.z, b.w);
    XH[idx] = o;
}

#define GACC(vv, ww) \
    a0 += (ww) * b2f_lo((vv).x); a1 += (ww) * b2f_hi((vv).x); \
    a2 += (ww) * b2f_lo((vv).y); a3 += (ww) * b2f_hi((vv).y); \
    a4 += (ww) * b2f_lo((vv).z); a5 += (ww) * b2f_hi((vv).z); \
    a6 += (ww) * b2f_lo((vv).w); a7 += (ww) * b2f_hi((vv).w);

// Dual-direction bf16 gather, 96-col rows. blockDim = (12, 32). Unroll x4.
// direction->XCD-half swizzle: r = bid & 7; dir = r >= 4.
__global__ __launch_bounds__(384) void gather2_kernel(
    const uint4* __restrict__ xf, const uint4* __restrict__ xb,
    const int* __restrict__ offs_f, const u32* __restrict__ pf,
    const int* __restrict__ offs_b, const u32* __restrict__ pb,
    uint4* __restrict__ outf, uint4* __restrict__ outb, int N) {
    int bid = blockIdx.x;
    int rb = bid & 7;
    int dir = rb >> 2;
    int nblk = (bid >> 3) * 4 + (rb & 3);
    int n = nblk * 32 + threadIdx.y;
    if (n >= N) return;
    const uint4* x; const int* offs; const u32* pr; uint4* out;
    if (dir == 0) { x = xf; offs = offs_f; pr = pf; out = outf; }
    else          { x = xb; offs = offs_b; pr = pb; out = outb; }
    int c = threadIdx.x;  // 0..11
    int s0 = offs[n], s1 = offs[n + 1];
    float a0 = 0, a1 = 0, a2 = 0, a3 = 0, a4 = 0, a5 = 0, a6 = 0, a7 = 0;
    int o = s0;
    for (; o + 4 <= s1; o += 4) {
        u32 p0 = pr[o], p1 = pr[o + 1], p2 = pr[o + 2], p3 = pr[o + 3];
        uint4 v0 = x[(size_t)(p0 >> 16) * 12 + c];
        uint4 v1 = x[(size_t)(p1 >> 16) * 12 + c];
        uint4 v2 = x[(size_t)(p2 >> 16) * 12 + c];
        uint4 v3 = x[(size_t)(p3 >> 16) * 12 + c];
        float w0 = b2f_lo(p0), w1 = b2f_lo(p1), w2 = b2f_lo(p2), w3 = b2f_lo(p3);
        GACC(v0, w0) GACC(v1, w1) GACC(v2, w2) GACC(v3, w3)
    }
    for (; o < s1; ++o) {
        u32 p0 = pr[o];
        uint4 v0 = x[(size_t)(p0 >> 16) * 12 + c];
        float w0 = b2f_lo(p0);
        GACC(v0, w0)
    }
    size_t oi = (size_t)n * 12 + c;
    uint4 ov;
    ov.x = pack2(a0, a1); ov.y = pack2(a2, a3);
    ov.z = pack2(a4, a5); ov.w = pack2(a6, a7);
    out[oi] = ov;
}

// Dual-direction bf16 gather, 64-col rows (phase-H H-part). blockDim = (8, 48).
__global__ __launch_bounds__(384) void gather2h_kernel(
    const uint4* __restrict__ xf, const uint4* __restrict__ xb,
    const int* __restrict__ offs_f, const u32* __restrict__ pf,
    const int* __restrict__ offs_b, const u32* __restrict__ pb,
    uint4* __restrict__ outf, uint4* __restrict__ outb, int N) {
    int bid = blockIdx.x;
    int rb = bid & 7;
    int dir = rb >> 2;
    int nblk = (bid >> 3) * 4 + (rb & 3);
    int n = nblk * 48 + threadIdx.y;
    if (n >= N) return;
    const uint4* x; const int* offs; const u32* pr; uint4* out;
    if (dir == 0) { x = xf; offs = offs_f; pr = pf; out = outf; }
    else          { x = xb; offs = offs_b; pr = pb; out = outb; }
    int c = threadIdx.x;  // 0..7
    int s0 = offs[n], s1 = offs[n + 1];
    float a0 = 0, a1 = 0, a2 = 0, a3 = 0, a4 = 0, a5 = 0, a6 = 0, a7 = 0;
    int o = s0;
    for (; o + 4 <= s1; o += 4) {
        u32 p0 = pr[o], p1 = pr[o + 1], p2 = pr[o + 2], p3 = pr[o + 3];
        uint4 v0 = x[(size_t)(p0 >> 16) * 8 + c];
        uint4 v1 = x[(size_t)(p1 >> 16) * 8 + c];
        uint4 v2 = x[(size_t)(p2 >> 16) * 8 + c];
        uint4 v3 = x[(size_t)(p3 >> 16) * 8 + c];
        float w0 = b2f_lo(p0), w1 = b2f_lo(p1), w2 = b2f_lo(p2), w3 = b2f_lo(p3);
        GACC(v0, w0) GACC(v1, w1) GACC(v2, w2) GACC(v3, w3)
    }
    for (; o < s1; ++o) {
        u32 p0 = pr[o];
        uint4 v0 = x[(size_t)(p0 >> 16) * 8 + c];
        float w0 = b2f_lo(p0);
        GACC(v0, w0)
    }
    size_t oi = (size_t)n * 8 + c;
    uint4 ov;
    ov.x = pack2(a0, a1); ov.y = pack2(a2, a3);
    ov.z = pack2(a4, a5); ov.w = pack2(a6, a7);
    out[oi] = ov;
}

// Fuse + swizzle gate weights into MFMA-fragment-linear bf16, with the
// Chebyshev fold: seg0 = W00+W10-W02-W12, seg1 = W01, seg2 = W11,
// seg3 = 2*W02, seg4 = 2*W12. One thread per element.
__global__ void prep_weights_kernel(const float* __restrict__ Wz, const float* __restrict__ Wr,
                                    const float* __restrict__ Wh, u16* __restrict__ wf_all) {
    const int KS = 96 * 64;
    int idx = blockIdx.x * blockDim.x + threadIdx.x;
    if (idx >= 3 * 30720) return;
    int g = idx / 30720, i = idx - g * 30720;
    const float* W = (g == 0) ? Wz : (g == 1) ? Wr : Wh;
    int j = i & 7, lane = (i >> 3) & 63, ct = (i >> 9) & 3, kt = i >> 11;
    int k = kt * 32 + (lane >> 4) * 8 + j;
    int col = ct * 16 + (lane & 15);
    int m = k / 96, fr = k - m * 96;
    int e = fr * 64 + col;
    float v;
    if (m == 0)      v = W[e] + W[3 * KS + e] - W[2 * KS + e] - W[5 * KS + e];
    else if (m == 1) v = W[1 * KS + e];
    else if (m == 2) v = W[4 * KS + e];
    else if (m == 3) v = 2.f * W[2 * KS + e];
    else             v = 2.f * W[5 * KS + e];
    wf_all[idx] = f2b(v);
}

// Fused Z+R GEMM: A (5 matrices, [N,96]) read ONCE into registers; two-phase
// LDS weight staging. Writes Z (bf16) and HR = Hb*sigmoid(accR) (bf16).
__global__ __launch_bounds__(512) void gemm_zr_kernel(
    const u16* __restrict__ A0, const u16* __restrict__ A1, const u16* __restrict__ A2,
    const u16* __restrict__ A3, const u16* __restrict__ A4,
    const u16* __restrict__ wfZ, const u16* __restrict__ wfR,
    const float* __restrict__ bz, const float* __restrict__ br,
    u16* __restrict__ ZB, u16* __restrict__ HR, int N) {
    __shared__ u16 wl[30720];  // 61440 B -> 2 blocks/CU
    int t = threadIdx.x;
    {
        const uint4* src = (const uint4*)wfZ;
        uint4* dst = (uint4*)wl;
        for (int i = t; i < 3840; i += 512) dst[i] = src[i];
    }

    int lane = t & 63, w = t >> 6;
    int rowBase = blockIdx.x * 128 + w * 16;
    int arow = rowBase + (lane & 15);
    int cf = (lane >> 4) * 8;
    int rsub = (lane >> 4) * 4;

    // Load all 15 A fragments (held across both phases).
    short8 afr[15];
    const u16* As[5] = {A0, A1, A2, A3, A4};
#pragma unroll
    for (int m = 0; m < 5; ++m) {
        const u16* a = As[m] + (size_t)arow * 96 + cf;
        afr[m * 3 + 0] = *(const short8*)(a);
        afr[m * 3 + 1] = *(const short8*)(a + 32);
        afr[m * 3 + 2] = *(const short8*)(a + 64);
    }
    __syncthreads();

    // ---- phase Z ----
    {
        f32x4 acc[4];
#pragma unroll
        for (int ct = 0; ct < 4; ++ct) {
            float b = bz[ct * 16 + (lane & 15)];
            acc[ct] = (f32x4){b, b, b, b};
        }
#pragma unroll
        for (int ktg = 0; ktg < 15; ++ktg)
#pragma unroll
            for (int ct = 0; ct < 4; ++ct) {
                short8 bfrag = *(const short8*)(&wl[((ktg * 4 + ct) * 64 + lane) * 8]);
                acc[ct] = __builtin_amdgcn_mfma_f32_16x16x32_bf16(afr[ktg], bfrag, acc[ct], 0, 0, 0);
            }
#pragma unroll
        for (int ct = 0; ct < 4; ++ct) {
            int col = ct * 16 + (lane & 15);
#pragma unroll
            for (int j = 0; j < 4; ++j) {
                int grow = rowBase + rsub + j;
                if (grow >= N) continue;
                ZB[(size_t)grow * 64 + col] = f2b(sigmoidf_(acc[ct][j]));
            }
        }
    }
    __syncthreads();  // all reads of wl (Z weights) done
    {
        const uint4* src = (const uint4*)wfR;
        uint4* dst = (uint4*)wl;
        for (int i = t; i < 3840; i += 512) dst[i] = src[i];
    }
    __syncthreads();

    // ---- phase R ----
    {
        f32x4 acc[4];
#pragma unroll
        for (int ct = 0; ct < 4; ++ct) {
            float b = br[ct * 16 + (lane & 15)];
            acc[ct] = (f32x4){b, b, b, b};
        }
#pragma unroll
        for (int ktg = 0; ktg < 15; ++ktg)
#pragma unroll
            for (int ct = 0; ct < 4; ++ct) {
                short8 bfrag = *(const short8*)(&wl[((ktg * 4 + ct) * 64 + lane) * 8]);
                acc[ct] = __builtin_amdgcn_mfma_f32_16x16x32_bf16(afr[ktg], bfrag, acc[ct], 0, 0, 0);
            }
#pragma unroll
        for (int ct = 0; ct < 4; ++ct) {
            int col = ct * 16 + (lane & 15);
#pragma unroll
            for (int j = 0; j < 4; ++j) {
                int grow = rowBase + rsub + j;
                if (grow >= N) continue;
                // Hb from XH's bf16 H-columns (A0 = XH)
                float hb = b2f_lo((u32)A0[(size_t)grow * 96 + 32 + col]);
                HR[(size_t)grow * 64 + col] = f2b(hb * sigmoidf_(acc[ct][j]));
            }
        }
    }
}

// H~ GEMM + GRU combine: A split (X-part stride 96 from ZR buffers, H-part
// stride 64). out = Z*H + (1-Z)*tanh(acc), Z read as bf16, H f32.
__global__ __launch_bounds__(512) void gemm_h_kernel(
    const u16* __restrict__ AX0, const u16* __restrict__ AX1, const u16* __restrict__ AX2,
    const u16* __restrict__ AX3, const u16* __restrict__ AX4,
    const u16* __restrict__ AH0, const u16* __restrict__ AH1, const u16* __restrict__ AH2,
    const u16* __restrict__ AH3, const u16* __restrict__ AH4,
    const u16* __restrict__ wfrag, const float* __restrict__ bias,
    const float* __restrict__ H, const u16* __restrict__ ZB,
    float* __restrict__ Out, int N) {
    __shared__ u16 wl[30720];
    int t = threadIdx.x;
    {
        const uint4* src = (const uint4*)wfrag;
        uint4* dst = (uint4*)wl;
        for (int i = t; i < 3840; i += 512) dst[i] = src[i];
    }
    __syncthreads();

    int lane = t & 63, w = t >> 6;
    int rowBase = blockIdx.x * 128 + w * 16;
    int arow = rowBase + (lane & 15);
    int cf = (lane >> 4) * 8;

    f32x4 acc[4];
#pragma unroll
    for (int ct = 0; ct < 4; ++ct) {
        float b = bias[ct * 16 + (lane & 15)];
        acc[ct] = (f32x4){b, b, b, b};
    }

    const u16* AXs[5] = {AX0, AX1, AX2, AX3, AX4};
    const u16* AHs[5] = {AH0, AH1, AH2, AH3, AH4};
#pragma unroll
    for (int m = 0; m < 5; ++m) {
        const u16* ax = AXs[m] + (size_t)arow * 96 + cf;
        const u16* ah = AHs[m] + (size_t)arow * 64 + cf;
#pragma unroll
        for (int k3 = 0; k3 < 3; ++k3) {
            short8 a = (k3 == 0) ? *(const short8*)ax
                                 : *(const short8*)(ah + (k3 - 1) * 32);
            int ktg = m * 3 + k3;
#pragma unroll
            for (int ct = 0; ct < 4; ++ct) {
                short8 b = *(const short8*)(&wl[((ktg * 4 + ct) * 64 + lane) * 8]);
                acc[ct] = __builtin_amdgcn_mfma_f32_16x16x32_bf16(a, b, acc[ct], 0, 0, 0);
            }
        }
    }

    int rsub = (lane >> 4) * 4;
#pragma unroll
    for (int ct = 0; ct < 4; ++ct) {
        int col = ct * 16 + (lane & 15);
#pragma unroll
        for (int j = 0; j < 4; ++j) {
            int grow = rowBase + rsub + j;
            if (grow >= N) continue;
            size_t bi = (size_t)grow * 64 + col;
            float z = b2f_lo((u32)ZB[bi]);
            Out[bi] = z * H[bi] + (1.f - z) * tanhf(acc[ct][j]);
        }
    }
}

// ---------------------------------------------------------------- launch

extern "C" void kernel_launch(void* const* d_in, const int* in_sizes, int n_in,
                              void* d_out, int out_size, void* d_ws, size_t ws_size,
                              hipStream_t stream) {
    const float* X  = (const float*)d_in[0];
    const int*   ei = (const int*)d_in[1];
    const float* ew = (const float*)d_in[2];
    const float* H  = (const float*)d_in[3];
    const float* Wz = (const float*)d_in[4];
    const float* bz = (const float*)d_in[5];
    const float* Wr = (const float*)d_in[6];
    const float* br = (const float*)d_in[7];
    const float* Wh = (const float*)d_in[8];
    const float* bh = (const float*)d_in[9];
    float* out = (float*)d_out;

    const int N = in_sizes[0] / 32;   // 50000
    const int E = in_sizes[2];        // 800000
    const int NB = (N + BKT_NODES - 1) >> BKT_BITS;  // 49 (code assumes NB <= 64)

    // ---- workspace carve (256B aligned) ----
    char* wp = (char*)d_ws;
    auto alloc = [&](size_t nbytes) -> void* {
        void* p = (void*)wp;
        wp += (nbytes + 255) & ~(size_t)255;
        return p;
    };
    u16* XH   = (u16*)alloc((size_t)N * 96 * 2);   // [X|H], stays intact
    u16* T1o  = (u16*)alloc((size_t)N * 96 * 2);
    u16* T1i  = (u16*)alloc((size_t)N * 96 * 2);
    u16* U2o  = (u16*)alloc((size_t)N * 96 * 2);   // plain P*T1 (fold in W)
    u16* U2i  = (u16*)alloc((size_t)N * 96 * 2);
    u16* HR   = (u16*)alloc((size_t)N * 64 * 2);   // H*R (phase-H H-part)
    u16* T1oH = (u16*)alloc((size_t)N * 64 * 2);
    u16* T1iH = (u16*)alloc((size_t)N * 64 * 2);
    u16* U2oH = (u16*)alloc((size_t)N * 64 * 2);
    u16* U2iH = (u16*)alloc((size_t)N * 64 * 2);
    u16* ZB   = (u16*)alloc((size_t)N * 64 * 2);   // Z gate, bf16
    float* deg_in  = (float*)alloc((size_t)N * 4);
    float* deg_out = (float*)alloc((size_t)N * 4);
    int* offs_f = (int*)alloc((size_t)(N + 1) * 4);
    int* offs_b = (int*)alloc((size_t)(N + 1) * 4);
    u32* pair_f = (u32*)alloc((size_t)E * 4);
    u32* pair_b = (u32*)alloc((size_t)E * 4);
    uint2* stgF = (uint2*)alloc((size_t)NB * STG_CAP * 8);
    uint2* stgB = (uint2*)alloc((size_t)NB * STG_CAP * 8);
    int* cntG = (int*)alloc((size_t)2 * NB * BKT_NODES * BANDS * 4);  // 3.2 MB
    u16* wf_all = (u16*)alloc((size_t)3 * 30720 * 2);
    int* gCntF  = (int*)alloc(64 * 4);
    int* gCntB  = (int*)alloc(64 * 4);
    int* bBaseF = (int*)alloc(65 * 4);
    int* bBaseB = (int*)alloc(65 * 4);

    const int xhBlocks = (N * 12 + NTHREADS - 1) / NTHREADS;
    const int gemmBlocks = (N + 127) / 128;
    const int binBlocks = (E + 4095) / 4096;
    const int pwBlocks = (3 * 30720 + NTHREADS - 1) / NTHREADS;
    dim3 gatherBlock(12, 32);
    const int g2NodeBlks = (N + 31) / 32;               // per direction
    const int g2Grid = ((g2NodeBlks + 3) / 4) * 8;      // dir->XCD-half swizzle
    dim3 gatherHBlock(8, 48);
    const int ghNodeBlks = (N + 47) / 48;
    const int ghGrid = ((ghNodeBlks + 3) / 4) * 8;

    // ---- edge preprocessing (bucketed CSR build) ----
    hipMemsetAsync(gCntF, 0, 64 * 4, stream);
    hipMemsetAsync(gCntB, 0, 64 * 4, stream);

    prep_weights_kernel<<<pwBlocks, NTHREADS, 0, stream>>>(Wz, Wr, Wh, wf_all);
    bin_kernel<<<binBlocks, 1024, 0, stream>>>(ei, ew, gCntF, gCntB, stgF, stgB, E, NB);
    bktdeg_kernel<<<2 * NB + 1, 1024, 0, stream>>>(stgF, stgB, gCntF, gCntB,
                                                   deg_in, deg_out, cntG,
                                                   bBaseF, bBaseB, offs_f, offs_b,
                                                   N, NB, E);
    bktcsr_kernel<<<2 * NB, 1024, 0, stream>>>(stgF, stgB, gCntF, gCntB, bBaseF, bBaseB,
                                               cntG, deg_in, deg_out, offs_f, offs_b,
                                               pair_f, pair_b, N, NB);

    // ---- phase ZR: shared T matrices on XH = [X|H] (96-col gathers) ----
    build_xh_kernel<<<xhBlocks, NTHREADS, 0, stream>>>((const float4*)X, (const float4*)H,
                                                       (uint4*)XH, N);
    gather2_kernel<<<g2Grid, gatherBlock, 0, stream>>>(
        (const uint4*)XH, (const uint4*)XH, offs_f, pair_f, offs_b, pair_b,
        (uint4*)T1o, (uint4*)T1i, N);
    gather2_kernel<<<g2Grid, gatherBlock, 0, stream>>>(
        (const uint4*)T1o, (const uint4*)T1i, offs_f, pair_f, offs_b, pair_b,
        (uint4*)U2o, (uint4*)U2i, N);

    // Fused Z+R gates (A read once): Z -> ZB (bf16), HR = Hb*sigmoid (bf16)
    gemm_zr_kernel<<<gemmBlocks, 512, 0, stream>>>(
        XH, T1o, T1i, U2o, U2i, wf_all, wf_all + 30720, bz, br, ZB, HR, N);

    // ---- phase H: propagate only the 64-col H*R part (X-part reused from ZR) ----
    gather2h_kernel<<<ghGrid, gatherHBlock, 0, stream>>>(
        (const uint4*)HR, (const uint4*)HR, offs_f, pair_f, offs_b, pair_b,
        (uint4*)T1oH, (uint4*)T1iH, N);
    gather2h_kernel<<<ghGrid, gatherHBlock, 0, stream>>>(
        (const uint4*)T1oH, (const uint4*)T1iH, offs_f, pair_f, offs_b, pair_b,
        (uint4*)U2oH, (uint4*)U2iH, N);

    // H~ gate + GRU combine fused; A = [X-part from ZR buffers | H-part 64-col]
    gemm_h_kernel<<<gemmBlocks, 512, 0, stream>>>(
        XH, T1o, T1i, U2o, U2i, HR, T1oH, T1iH, U2oH, U2iH,
        wf_all + 2 * 30720, bh, H, ZB, out, N);
}